// Round 14
// baseline (380.857 us; speedup 1.0000x reference)
//
#include <hip/hip_runtime.h>

#define N_TOT  200000
#define NG_    100000
#define NU_    100000
#define E_CNT  3200000
#define C_CNT  1000000

#define NBUCK  196        // ceil(NG_/512): bucket k covers nodes [k*512, k*512+512)
#define NBLK   256        // edge chunks
#define CHUNK  12500      // E_CNT / NBLK exactly

// fallback (round-5) candidate chunking
#define CBLK   250
#define CCHUNK 4000
// ext (fused) candidate chunking: 256 chunks of 3907 (last block short)
#define CCH_E  3907

// fallback phaseD LDS staging capacity
#define DCAP   17920

// ======================= ext-path kernels =======================

// ---- zeroN: clear per-node counters (workspace is poison-filled each iter) ----
__global__ __launch_bounds__(1024) void zeroN(int* __restrict__ node_cnt) {
    int i = blockIdx.x * 1024 + threadIdx.x;
    if (i < NG_) node_cnt[i] = 0;
}

// ---- phaseA_f: edge histogram (bucket LDS + per-node global fire-and-forget)
//      + candidate histogram; 1024 thr (16 waves/CU) ----
__global__ __launch_bounds__(1024) void phaseA_f(const int* __restrict__ dst,
                                                 const int* __restrict__ cand,
                                                 int* __restrict__ cnt_mat,
                                                 int* __restrict__ cnt2,
                                                 int* __restrict__ node_cnt) {
    __shared__ int hcnt[NBUCK];
    int t = threadIdx.x;
    if (t < NBUCK) hcnt[t] = 0;
    __syncthreads();
    int beg = blockIdx.x * CHUNK, end = beg + CHUNK;
    for (int e = beg + t; e < end; e += 1024) {
        int d = dst[e];
        atomicAdd(&hcnt[d >> 9], 1);
        atomicAdd(&node_cnt[d], 1);        // no-return global atomic (cheap, r8)
    }
    __syncthreads();
    if (t < NBUCK) { cnt_mat[blockIdx.x * NBUCK + t] = hcnt[t]; hcnt[t] = 0; }
    __syncthreads();
    int cbeg = blockIdx.x * CCH_E;
    int cend = min(cbeg + CCH_E, C_CNT);
    for (int e = cbeg + t; e < cend; e += 1024)
        atomicAdd(&hcnt[cand[2 * e] >> 9], 1);
    __syncthreads();
    if (t < NBUCK) cnt2[blockIdx.x * NBUCK + t] = hcnt[t];
}

// ---- phaseB1_f: 392 blocks; k<196 -> edge column scan, else cand column ----
__global__ __launch_bounds__(256) void phaseB1_f(const int* __restrict__ cnt_mat,
                                                 const int* __restrict__ cnt2,
                                                 int* __restrict__ off_mat,
                                                 int* __restrict__ off2,
                                                 int* __restrict__ colsum,
                                                 int* __restrict__ csum2) {
    __shared__ int s[256];
    int t = threadIdx.x;
    int k = blockIdx.x % NBUCK;
    bool is_cand = blockIdx.x >= NBUCK;
    const int* cm = is_cand ? cnt2 : cnt_mat;
    int v = cm[t * NBUCK + k];
    s[t] = v;
    __syncthreads();
    for (int off = 1; off < 256; off <<= 1) {
        int u = (t >= off) ? s[t - off] : 0;
        __syncthreads();
        s[t] += u;
        __syncthreads();
    }
    int* om = is_cand ? off2 : off_mat;
    om[t * NBUCK + k] = s[t] - v;
    if (t == 255) (is_cand ? csum2 : colsum)[k] = s[255];
}

// ---- phaseB2_f: both bucket-total scans + weight-prep fold ----
// wprep layout (floats): wT16[1024], wc0[64]@1024, wc1[64]@1088, bc[64]@1152
__global__ __launch_bounds__(256) void phaseB2_f(const int* __restrict__ colsum,
                                                 const int* __restrict__ csum2,
                                                 int* __restrict__ bbase,
                                                 int* __restrict__ bbase2,
                                                 const float* __restrict__ wu,
                                                 const float* __restrict__ bu,
                                                 const float* __restrict__ wa,
                                                 const float* __restrict__ ba,
                                                 float* __restrict__ wprep) {
    __shared__ int s[256];
    int t = threadIdx.x;
    int v = (t < NBUCK) ? colsum[t] : 0;
    s[t] = v;
    __syncthreads();
    for (int off = 1; off < 256; off <<= 1) {
        int u = (t >= off) ? s[t - off] : 0;
        __syncthreads();
        s[t] += u;
        __syncthreads();
    }
    if (t < NBUCK) bbase[t] = s[t] - v;
    if (t == NBUCK - 1) bbase[NBUCK] = s[t];
    __syncthreads();
    int v2 = (t < NBUCK) ? csum2[t] : 0;
    s[t] = v2;
    __syncthreads();
    for (int off = 1; off < 256; off <<= 1) {
        int u = (t >= off) ? s[t - off] : 0;
        __syncthreads();
        s[t] += u;
        __syncthreads();
    }
    if (t < NBUCK) bbase2[t] = s[t] - v2;
    if (t == NBUCK - 1) bbase2[NBUCK] = s[t];
    if (t < 64) {
        int j = t;
#pragma unroll
        for (int i = 0; i < 16; i++) wprep[j * 16 + i] = wa[i * 64 + j];
        float c0 = 0.f, c1 = 0.f, bc = ba[j];
#pragma unroll
        for (int k2 = 0; k2 < 16; k2++) {
            float w = wa[(16 + k2) * 64 + j];
            c0 += wu[k2] * w;
            c1 += wu[16 + k2] * w;
            bc += bu[k2] * w;
        }
        wprep[1024 + j] = c0;
        wprep[1088 + j] = c1;
        wprep[1152 + j] = bc;
    }
}

// ---- scanN: per-bucket 512-scan of node_cnt + bbase -> absolute node_off ----
// Sum of node_cnt within bucket k == colsum[k], so offsets exactly tile
// [bbase[k], bbase[k+1]). node_off[NG_] set to E_CNT explicitly.
__global__ __launch_bounds__(512) void scanN(const int* __restrict__ node_cnt,
                                             const int* __restrict__ bbase,
                                             int* __restrict__ node_off) {
    __shared__ int s[512];
    int k = blockIdx.x, t = threadIdx.x;
    int idx = (k << 9) + t;
    int v = (idx < NG_) ? node_cnt[idx] : 0;
    s[t] = v;
    __syncthreads();
    for (int off = 1; off < 512; off <<= 1) {
        int u = (t >= off) ? s[t - off] : 0;
        __syncthreads();
        s[t] += u;
        __syncthreads();
    }
    if (idx < NG_) node_off[idx] = bbase[k] + s[t] - v;
    if (k == 0 && t == 0) node_off[NG_] = E_CNT;
}

// ---- phaseC_f: edge + candidate bucket-scatter; 1024 thr (16 waves/CU) ----
// cand packing: w0 = g | (u<<17); w1 = (u>>15) | (idx<<2)
__global__ __launch_bounds__(1024) void phaseC_f(const int* __restrict__ src,
                                                 const int* __restrict__ dst,
                                                 const int* __restrict__ off_mat,
                                                 const int* __restrict__ bbase,
                                                 const int* __restrict__ cand,
                                                 const int* __restrict__ off2,
                                                 const int* __restrict__ bbase2,
                                                 int* __restrict__ pairs,
                                                 int2* __restrict__ sc) {
    __shared__ int loc[NBUCK];
    int t = threadIdx.x;
    if (t < NBUCK) loc[t] = bbase[t] + off_mat[blockIdx.x * NBUCK + t];
    __syncthreads();
    int beg = blockIdx.x * CHUNK, end = beg + CHUNK;
    for (int e = beg + t; e < end; e += 1024) {
        int d = dst[e], s = src[e];
        int k = d >> 9;
        int pos = atomicAdd(&loc[k], 1);
        pairs[pos] = (s << 9) | (d & 511);
    }
    __syncthreads();
    if (t < NBUCK) loc[t] = bbase2[t] + off2[blockIdx.x * NBUCK + t];
    __syncthreads();
    int cbeg = blockIdx.x * CCH_E;
    int cend = min(cbeg + CCH_E, C_CNT);
    for (int e = cbeg + t; e < cend; e += 1024) {
        int g = cand[2 * e], u = cand[2 * e + 1];
        int k = g >> 9;
        int pos = atomicAdd(&loc[k], 1);
        int w0 = g | (u << 17);
        int w1 = (int)(((unsigned)u >> 15) | ((unsigned)e << 2));
        sc[pos] = make_int2(w0, w1);
    }
}

// ---- phaseD2: SINGLE-pass CSR scatter (cursors preloaded from node_off) ----
// Replaces the count-pass + scan of the old phaseD: per-node counts came from
// phaseA_f's global histogram via scanN. One LDS return-atomic per edge.
__global__ __launch_bounds__(1024) void phaseD2(const int* __restrict__ bbase,
                                                const int* __restrict__ node_off,
                                                const int* __restrict__ pairs,
                                                int* __restrict__ csr_src) {
    __shared__ int cur[512];
    int t = threadIdx.x, k = blockIdx.x;
    if (t < 512) {
        int idx = (k << 9) + t;
        cur[t] = (idx < NG_) ? node_off[idx] : 0;   // bins past NG_ never used
    }
    __syncthreads();
    int beg = bbase[k], end = bbase[k + 1];
    for (int e = beg + t; e < end; e += 1024) {
        int p = pairs[e];
        int pos = atomicAdd(&cur[p & 511], 1);
        csr_src[pos] = p >> 9;
    }
}

// ======================= fallback (round-5) kernels =======================

__global__ __launch_bounds__(256) void phaseA(const int* __restrict__ dst,
                                              int* __restrict__ cnt_mat) {
    __shared__ int hcnt[NBUCK];
    int t = threadIdx.x;
    if (t < NBUCK) hcnt[t] = 0;
    __syncthreads();
    int beg = blockIdx.x * CHUNK, end = beg + CHUNK;
    for (int e = beg + t; e < end; e += 256)
        atomicAdd(&hcnt[dst[e] >> 9], 1);
    __syncthreads();
    if (t < NBUCK) cnt_mat[blockIdx.x * NBUCK + t] = hcnt[t];
}

__global__ __launch_bounds__(256) void phaseB1(const int* __restrict__ cnt_mat,
                                               int* __restrict__ off_mat,
                                               int* __restrict__ colsum) {
    __shared__ int s[256];
    int t = threadIdx.x;
    int k = blockIdx.x;
    int v = cnt_mat[t * NBUCK + k];
    s[t] = v;
    __syncthreads();
    for (int off = 1; off < 256; off <<= 1) {
        int u = (t >= off) ? s[t - off] : 0;
        __syncthreads();
        s[t] += u;
        __syncthreads();
    }
    off_mat[t * NBUCK + k] = s[t] - v;
    if (t == 255) colsum[k] = s[255];
}

__global__ __launch_bounds__(256) void phaseB2(const int* __restrict__ colsum,
                                               int* __restrict__ bbase) {
    __shared__ int s[256];
    int t = threadIdx.x;
    int v = (t < NBUCK) ? colsum[t] : 0;
    s[t] = v;
    __syncthreads();
    for (int off = 1; off < 256; off <<= 1) {
        int u = (t >= off) ? s[t - off] : 0;
        __syncthreads();
        s[t] += u;
        __syncthreads();
    }
    if (t < NBUCK) bbase[t] = s[t] - v;
    if (t == NBUCK - 1) bbase[NBUCK] = s[t];
}

__global__ __launch_bounds__(256) void phaseC(const int* __restrict__ src,
                                              const int* __restrict__ dst,
                                              const int* __restrict__ off_mat,
                                              const int* __restrict__ bbase,
                                              int* __restrict__ pairs) {
    __shared__ int loc[NBUCK];
    int t = threadIdx.x;
    if (t < NBUCK) loc[t] = bbase[t] + off_mat[blockIdx.x * NBUCK + t];
    __syncthreads();
    int beg = blockIdx.x * CHUNK, end = beg + CHUNK;
    for (int e = beg + t; e < end; e += 256) {
        int d = dst[e], s = src[e];
        int k = d >> 9;
        int pos = atomicAdd(&loc[k], 1);
        pairs[pos] = (s << 9) | (d & 511);
    }
}

__global__ void prep_kernel(const float* __restrict__ wu,
                            const float* __restrict__ bu,
                            const float* __restrict__ wa,
                            const float* __restrict__ ba,
                            float* __restrict__ wprep) {
    int j = threadIdx.x;   // 64 threads
#pragma unroll
    for (int i = 0; i < 16; i++) wprep[j * 16 + i] = wa[i * 64 + j];
    float c0 = 0.f, c1 = 0.f, bc = ba[j];
#pragma unroll
    for (int k = 0; k < 16; k++) {
        float w = wa[(16 + k) * 64 + j];
        c0 += wu[k] * w;
        c1 += wu[16 + k] * w;
        bc += bu[k] * w;
    }
    wprep[1024 + j] = c0;
    wprep[1088 + j] = c1;
    wprep[1152 + j] = bc;
}

__global__ __launch_bounds__(256) void candA(const int* __restrict__ cand,
                                             int* __restrict__ cnt2) {
    __shared__ int hcnt[NBUCK];
    int t = threadIdx.x;
    if (t < NBUCK) hcnt[t] = 0;
    __syncthreads();
    int beg = blockIdx.x * CCHUNK, end = beg + CCHUNK;
    for (int e = beg + t; e < end; e += 256)
        atomicAdd(&hcnt[cand[2 * e] >> 9], 1);
    __syncthreads();
    if (t < NBUCK) cnt2[blockIdx.x * NBUCK + t] = hcnt[t];
}

__global__ __launch_bounds__(256) void candB1(const int* __restrict__ cnt2,
                                              int* __restrict__ off2,
                                              int* __restrict__ csum2) {
    __shared__ int s[256];
    int t = threadIdx.x;
    int k = blockIdx.x;
    int v = (t < CBLK) ? cnt2[t * NBUCK + k] : 0;
    s[t] = v;
    __syncthreads();
    for (int off = 1; off < 256; off <<= 1) {
        int u = (t >= off) ? s[t - off] : 0;
        __syncthreads();
        s[t] += u;
        __syncthreads();
    }
    if (t < CBLK) off2[t * NBUCK + k] = s[t] - v;
    if (t == 255) csum2[k] = s[255];
}

__global__ __launch_bounds__(256) void candB2(const int* __restrict__ csum2,
                                              int* __restrict__ bbase2) {
    __shared__ int s[256];
    int t = threadIdx.x;
    int v = (t < NBUCK) ? csum2[t] : 0;
    s[t] = v;
    __syncthreads();
    for (int off = 1; off < 256; off <<= 1) {
        int u = (t >= off) ? s[t - off] : 0;
        __syncthreads();
        s[t] += u;
        __syncthreads();
    }
    if (t < NBUCK) bbase2[t] = s[t] - v;
    if (t == NBUCK - 1) bbase2[NBUCK] = s[t];
}

__global__ __launch_bounds__(256) void candC(const int* __restrict__ cand,
                                             const int* __restrict__ off2,
                                             const int* __restrict__ bbase2,
                                             int2* __restrict__ sc) {
    __shared__ int loc[NBUCK];
    int t = threadIdx.x;
    if (t < NBUCK) loc[t] = bbase2[t] + off2[blockIdx.x * NBUCK + t];
    __syncthreads();
    int beg = blockIdx.x * CCHUNK, end = beg + CCHUNK;
    for (int e = beg + t; e < end; e += 256) {
        int g = cand[2 * e], u = cand[2 * e + 1];
        int k = g >> 9;
        int pos = atomicAdd(&loc[k], 1);
        int w0 = g | (u << 17);
        int w1 = (int)(((unsigned)u >> 15) | ((unsigned)e << 2));
        sc[pos] = make_int2(w0, w1);
    }
}

// ---- fallback phaseD: two-pass counting sort with LDS pair staging ----
__global__ __launch_bounds__(1024) void phaseD(const int* __restrict__ bbase,
                                               const int* __restrict__ pairs,
                                               int* __restrict__ csr_src,
                                               int* __restrict__ node_off) {
    __shared__ int cnt[512], scn[512], base[512];
    __shared__ int lpairs[DCAP];
    int t = threadIdx.x, k = blockIdx.x;
    if (t < 512) cnt[t] = 0;
    __syncthreads();
    int beg = bbase[k], end = bbase[k + 1];
    int len = end - beg;
    for (int i = t; i < len; i += 1024) {
        int p = pairs[beg + i];
        if (i < DCAP) lpairs[i] = p;
        atomicAdd(&cnt[p & 511], 1);
    }
    __syncthreads();
    if (t < 512) scn[t] = cnt[t];
    __syncthreads();
    for (int off = 1; off < 512; off <<= 1) {
        int v = 0;
        if (t < 512 && t >= off) v = scn[t - off];
        __syncthreads();
        if (t < 512) scn[t] += v;
        __syncthreads();
    }
    if (t < 512) {
        int bse = beg + scn[t] - cnt[t];
        base[t] = bse;
        node_off[(k << 9) + t] = bse;
    }
    __syncthreads();
    for (int i = t; i < len; i += 1024) {
        int p = (i < DCAP) ? lpairs[i] : pairs[beg + i];
        int pos = atomicAdd(&base[p & 511], 1);
        csr_src[pos] = p >> 9;
    }
}

// ======================= shared pipeline kernels =======================

// ---- conv1: CSR register aggregation, 8 lanes/node, 4-deep load pipeline ----
__global__ __launch_bounds__(256) void conv1_csr(const int* __restrict__ node_off,
                                                 const int* __restrict__ csr_src,
                                                 const float* __restrict__ x,
                                                 const float* __restrict__ w_rel,
                                                 const float* __restrict__ w_root,
                                                 const float* __restrict__ b,
                                                 float* __restrict__ h1) {
    int t = threadIdx.x;
    int n = blockIdx.x * 32 + (t >> 3);
    int l = t & 7;
    int beg = node_off[n], end = node_off[n + 1];
    float a0 = 0.f, a1 = 0.f, b0 = 0.f, b1v = 0.f;
    float c0 = 0.f, c1 = 0.f, d0 = 0.f, d1 = 0.f;
    int e = beg + l;
    for (; e + 24 < end; e += 32) {
        int s0 = csr_src[e];
        int s1 = csr_src[e + 8];
        int s2 = csr_src[e + 16];
        int s3 = csr_src[e + 24];
        float2 v0 = *(const float2*)(x + 2 * s0);
        float2 v1 = *(const float2*)(x + 2 * s1);
        float2 v2 = *(const float2*)(x + 2 * s2);
        float2 v3 = *(const float2*)(x + 2 * s3);
        a0 += v0.x; a1 += v0.y;
        b0 += v1.x; b1v += v1.y;
        c0 += v2.x; c1 += v2.y;
        d0 += v3.x; d1 += v3.y;
    }
    for (; e < end; e += 8) {
        int s0 = csr_src[e];
        float2 v0 = *(const float2*)(x + 2 * s0);
        a0 += v0.x; a1 += v0.y;
    }
    a0 += b0 + c0 + d0;
    a1 += b1v + c1 + d1;
#pragma unroll
    for (int d = 1; d < 8; d <<= 1) {
        a0 += __shfl_xor(a0, d, 64);
        a1 += __shfl_xor(a1, d, 64);
    }
    float2 xn = *(const float2*)(x + 2 * n);
    float v = a0 * w_rel[l] + a1 * w_rel[8 + l]
            + xn.x * w_root[l] + xn.y * w_root[8 + l] + b[l];
    h1[8 * n + l] = fmaxf(v, 0.f);
}

// ---- conv2_ag16: conv2 + precompA fused, 16 lanes/node, paired-line gather,
//      4-deep load pipeline ----
__global__ __launch_bounds__(256) void conv2_ag16(const int* __restrict__ node_off,
                                                  const int* __restrict__ csr_src,
                                                  const float* __restrict__ h1,
                                                  const float* __restrict__ w_rel,
                                                  const float* __restrict__ w_root,
                                                  const float* __restrict__ b,
                                                  const float* __restrict__ wa,
                                                  const float* __restrict__ wprep,
                                                  float* __restrict__ Ag) {
    __shared__ float sh[16][17];   // h2 staging, +1 pad
    int t = threadIdx.x;
    int g = t >> 4, l = t & 15;    // 16 nodes/block, 16 lanes/node
    int pr = l & 1, pe = l >> 1;   // pr: row half, pe: edge slot (0..7)
    int n = blockIdx.x * 16 + g;   // grid 6250*16 == 100000 exactly
    int beg = node_off[n], end = node_off[n + 1];
    float4 a4 = make_float4(0.f, 0.f, 0.f, 0.f);
    float4 b4 = make_float4(0.f, 0.f, 0.f, 0.f);
    float4 c4 = make_float4(0.f, 0.f, 0.f, 0.f);
    float4 d4 = make_float4(0.f, 0.f, 0.f, 0.f);
    int e = beg + pe;
    for (; e + 24 < end; e += 32) {
        int s0 = csr_src[e];
        int s1 = csr_src[e + 8];
        int s2 = csr_src[e + 16];
        int s3 = csr_src[e + 24];
        float4 v0 = *(const float4*)(h1 + 8 * s0 + 4 * pr);
        float4 v1 = *(const float4*)(h1 + 8 * s1 + 4 * pr);
        float4 v2 = *(const float4*)(h1 + 8 * s2 + 4 * pr);
        float4 v3 = *(const float4*)(h1 + 8 * s3 + 4 * pr);
        a4.x += v0.x; a4.y += v0.y; a4.z += v0.z; a4.w += v0.w;
        b4.x += v1.x; b4.y += v1.y; b4.z += v1.z; b4.w += v1.w;
        c4.x += v2.x; c4.y += v2.y; c4.z += v2.z; c4.w += v2.w;
        d4.x += v3.x; d4.y += v3.y; d4.z += v3.z; d4.w += v3.w;
    }
    for (; e < end; e += 8) {
        int s0 = csr_src[e];
        float4 v0 = *(const float4*)(h1 + 8 * s0 + 4 * pr);
        a4.x += v0.x; a4.y += v0.y; a4.z += v0.z; a4.w += v0.w;
    }
    a4.x += b4.x + c4.x + d4.x;
    a4.y += b4.y + c4.y + d4.y;
    a4.z += b4.z + c4.z + d4.z;
    a4.w += b4.w + c4.w + d4.w;
#pragma unroll
    for (int d = 2; d < 16; d <<= 1) {
        a4.x += __shfl_xor(a4.x, d);
        a4.y += __shfl_xor(a4.y, d);
        a4.z += __shfl_xor(a4.z, d);
        a4.w += __shfl_xor(a4.w, d);
    }
    float o0 = __shfl_xor(a4.x, 1), o1 = __shfl_xor(a4.y, 1);
    float o2 = __shfl_xor(a4.z, 1), o3 = __shfl_xor(a4.w, 1);
    float agg[8];
    if (pr == 0) {
        agg[0] = a4.x; agg[1] = a4.y; agg[2] = a4.z; agg[3] = a4.w;
        agg[4] = o0;   agg[5] = o1;   agg[6] = o2;   agg[7] = o3;
    } else {
        agg[0] = o0;   agg[1] = o1;   agg[2] = o2;   agg[3] = o3;
        agg[4] = a4.x; agg[5] = a4.y; agg[6] = a4.z; agg[7] = a4.w;
    }
    const float4* hp = (const float4*)(h1 + 8 * n);
    float4 t0 = hp[0], t1 = hp[1];
    float hn[8] = {t0.x, t0.y, t0.z, t0.w, t1.x, t1.y, t1.z, t1.w};
    {
        int c = l;
        float v = b[c];
#pragma unroll
        for (int j = 0; j < 8; j++)
            v += agg[j] * w_rel[j * 16 + c] + hn[j] * w_root[j * 16 + c];
        sh[g][c] = fmaxf(v, 0.f);
    }
    __syncthreads();
    float4 a = *(const float4*)(wprep + 1152 + 4 * l);
#pragma unroll
    for (int i = 0; i < 16; i++) {
        float hi = sh[g][i];
        float4 w = *(const float4*)(wa + i * 64 + 4 * l);
        a.x += hi * w.x; a.y += hi * w.y; a.z += hi * w.z; a.w += hi * w.w;
    }
    *(float4*)(Ag + 64 * n + 4 * l) = a;
}

// ---- fallback: conv2 writing h2 + separate precompA (Ag overlays csr there) ----
__global__ __launch_bounds__(256) void conv2_csr(const int* __restrict__ node_off,
                                                 const int* __restrict__ csr_src,
                                                 const float* __restrict__ h1,
                                                 const float* __restrict__ w_rel,
                                                 const float* __restrict__ w_root,
                                                 const float* __restrict__ b,
                                                 float* __restrict__ h2) {
    int t = threadIdx.x;
    int n = blockIdx.x * 32 + (t >> 3);
    int l = t & 7;
    int beg = node_off[n], end = node_off[n + 1];
    float acc[8] = {0.f, 0.f, 0.f, 0.f, 0.f, 0.f, 0.f, 0.f};
    for (int e = beg + l; e < end; e += 8) {
        int s = csr_src[e];
        const float4* hp = (const float4*)(h1 + 8 * s);
        float4 v0 = hp[0], v1 = hp[1];
        acc[0] += v0.x; acc[1] += v0.y; acc[2] += v0.z; acc[3] += v0.w;
        acc[4] += v1.x; acc[5] += v1.y; acc[6] += v1.z; acc[7] += v1.w;
    }
#pragma unroll
    for (int d = 1; d < 8; d <<= 1)
#pragma unroll
        for (int j = 0; j < 8; j++)
            acc[j] += __shfl_xor(acc[j], d, 64);
    const float4* hp = (const float4*)(h1 + 8 * n);
    float4 t0 = hp[0], t1 = hp[1];
    float hn[8] = {t0.x, t0.y, t0.z, t0.w, t1.x, t1.y, t1.z, t1.w};
#pragma unroll
    for (int cc = 0; cc < 2; cc++) {
        int c = l + 8 * cc;
        float v = b[c];
#pragma unroll
        for (int j = 0; j < 8; j++)
            v += acc[j] * w_rel[j * 16 + c] + hn[j] * w_root[j * 16 + c];
        h2[16 * n + c] = fmaxf(v, 0.f);
    }
}

__global__ __launch_bounds__(256) void precompA(const float* __restrict__ h2,
                                                const float* __restrict__ wa,
                                                const float* __restrict__ wprep,
                                                float* __restrict__ Ag) {
    int g = blockIdx.x * 256 + threadIdx.x;
    if (g >= NG_) return;
    float h[16];
    const float4* hp = (const float4*)(h2 + 16 * g);
#pragma unroll
    for (int q = 0; q < 4; q++) {
        float4 v = hp[q];
        h[4*q] = v.x; h[4*q+1] = v.y; h[4*q+2] = v.z; h[4*q+3] = v.w;
    }
    float4* op = (float4*)(Ag + 64 * g);
#pragma unroll
    for (int q = 0; q < 16; q++) {
        float4 v;
        v.x = wprep[1152 + 4*q + 0];
        v.y = wprep[1152 + 4*q + 1];
        v.z = wprep[1152 + 4*q + 2];
        v.w = wprep[1152 + 4*q + 3];
#pragma unroll
        for (int i = 0; i < 16; i++) {
            float hi = h[i];
            v.x += hi * wa[i*64 + 4*q + 0];
            v.y += hi * wa[i*64 + 4*q + 1];
            v.z += hi * wa[i*64 + 4*q + 2];
            v.w += hi * wa[i*64 + 4*q + 3];
        }
        op[q] = v;
    }
}

// ---- final MLP v7: 8 lanes per candidate, coalesced 256B row reads ----
__global__ __launch_bounds__(256) void final_mlp7(const int2* __restrict__ sc,
                                                  const float* __restrict__ Ag,
                                                  const float* __restrict__ x,
                                                  const float* __restrict__ wprep,
                                                  const float* __restrict__ wb,
                                                  const float* __restrict__ bb,
                                                  float* __restrict__ out) {
    // m204 bijective chunked swizzle (keep sorted candidates XCD-local)
    int nwg = gridDim.x;
    int xcd = blockIdx.x & 7, pos = blockIdx.x >> 3;
    int q = nwg >> 3, r = nwg & 7;
    int wg = (xcd < r ? xcd * (q + 1) : r * (q + 1) + (xcd - r) * q) + pos;

    int t = threadIdx.x;
    int l = t & 7;
    int grp = t >> 3;
    float4 c0lo = *(const float4*)(wprep + 1024 + 4 * l);
    float4 c0hi = *(const float4*)(wprep + 1024 + 32 + 4 * l);
    float4 c1lo = *(const float4*)(wprep + 1088 + 4 * l);
    float4 c1hi = *(const float4*)(wprep + 1088 + 32 + 4 * l);
    float4 wblo = *(const float4*)(wb + 4 * l);
    float4 wbhi = *(const float4*)(wb + 32 + 4 * l);
    float bb0 = bb[0];

    int base = wg * 256;
#pragma unroll 2
    for (int it = 0; it < 8; ++it) {
        int c = base + it * 32 + grp;
        if (c < C_CNT) {
            int2 w = sc[c];
            unsigned w0 = (unsigned)w.x, w1 = (unsigned)w.y;
            int g   = (int)(w0 & 0x1FFFFu);
            int u   = (int)((w0 >> 17) | ((w1 & 3u) << 15));
            int idx = (int)(w1 >> 2);
            float2 xv = *(const float2*)(x + 2 * (NG_ + u));
            const float* rp = Ag + 64 * g;
            float4 alo = *(const float4*)(rp + 4 * l);
            float4 ahi = *(const float4*)(rp + 32 + 4 * l);
            float acc;
            {
                float v0 = alo.x + xv.x * c0lo.x + xv.y * c1lo.x;
                float v1 = alo.y + xv.x * c0lo.y + xv.y * c1lo.y;
                float v2 = alo.z + xv.x * c0lo.z + xv.y * c1lo.z;
                float v3 = alo.w + xv.x * c0lo.w + xv.y * c1lo.w;
                acc  = fmaxf(v0, 0.f) * wblo.x;
                acc += fmaxf(v1, 0.f) * wblo.y;
                acc += fmaxf(v2, 0.f) * wblo.z;
                acc += fmaxf(v3, 0.f) * wblo.w;
            }
            {
                float v0 = ahi.x + xv.x * c0hi.x + xv.y * c1hi.x;
                float v1 = ahi.y + xv.x * c0hi.y + xv.y * c1hi.y;
                float v2 = ahi.z + xv.x * c0hi.z + xv.y * c1hi.z;
                float v3 = ahi.w + xv.x * c0hi.w + xv.y * c1hi.w;
                acc += fmaxf(v0, 0.f) * wbhi.x;
                acc += fmaxf(v1, 0.f) * wbhi.y;
                acc += fmaxf(v2, 0.f) * wbhi.z;
                acc += fmaxf(v3, 0.f) * wbhi.w;
            }
            acc += __shfl_xor(acc, 1);
            acc += __shfl_xor(acc, 2);
            acc += __shfl_xor(acc, 4);
            if (l == 0) out[idx] = acc + bb0;
        }
    }
}

// ======================= launch =======================

extern "C" void kernel_launch(void* const* d_in, const int* in_sizes, int n_in,
                              void* d_out, int out_size, void* d_ws, size_t ws_size,
                              hipStream_t stream) {
    const float* x      = (const float*)d_in[0];
    const int*   cand   = (const int*)d_in[2];
    const int*   edges  = (const int*)d_in[3];   // [2, E]: src then dst
    const float* w1_rel = (const float*)d_in[4];
    const float* w1_root= (const float*)d_in[5];
    const float* b1     = (const float*)d_in[6];
    const float* w2_rel = (const float*)d_in[7];
    const float* w2_root= (const float*)d_in[8];
    const float* b2     = (const float*)d_in[9];
    const float* wu     = (const float*)d_in[10];
    const float* bu     = (const float*)d_in[11];
    const float* wa     = (const float*)d_in[12];
    const float* ba     = (const float*)d_in[13];
    const float* wb     = (const float*)d_in[14];
    const float* bb     = (const float*)d_in[15];
    float* out = (float*)d_out;

    const int* src = edges;
    const int* dst = edges + E_CNT;

    // Base layout (int units), 9,002,944 ints = 36.0 MB:
    //   cnt_mat  [0         .. 50,176)
    //   off_mat  [50,176    .. 100,352)
    //   colsum   [100,352   .. 100,548)
    //   bbase    [100,608   .. 100,805)
    //   node_off [100,864   .. 201,728)
    //   wprep    [201,728   .. 202,944)
    //   pairs    [202,944   .. 3,402,944)
    //   csr_src  [3,402,944 .. 6,602,944)
    //   h1 (f)   [6,602,944 .. 7,402,944)
    //   h2 (f)   [7,402,944 .. 9,002,944)   (fallback only)
    // EXT extras (needs 17,603,808 ints = 70.4 MB; harness fill showed 256 MiB):
    //   cnt2     [9,002,944 .. 9,053,120)
    //   off2     [9,053,120 .. 9,103,296)
    //   csum2    [9,103,296 .. 9,103,492)  pad-> 9,103,552
    //   bbase2   [9,103,552 .. 9,103,749)  pad-> 9,103,808
    //   sc       [9,103,808 .. 11,103,808)  (1M int2, 8B-aligned)
    //   Ag       [11,103,808 .. 17,503,808) (6.4M floats)
    //   node_cnt [17,503,808 .. 17,603,808) (100K ints)
    // FALLBACK (round-5 proven): cnt2/off2/csum2/bbase2 overlay cnt_mat/off_mat/
    //   colsum/bbase; Ag overlays pairs+csr; sc overlays h1+h2; sort after precompA.
    int* ws_i = (int*)d_ws;
    int*   cnt_mat  = ws_i;
    int*   off_mat  = ws_i + 50176;
    int*   colsum   = ws_i + 100352;
    int*   bbase    = ws_i + 100608;
    int*   node_off = ws_i + 100864;
    float* wprep    = (float*)(ws_i + 201728);
    int*   pairs    = ws_i + 202944;
    int*   csr_src  = ws_i + 3402944;
    float* h1       = (float*)(ws_i + 6602944);
    float* h2       = (float*)(ws_i + 7402944);

    bool ext = ws_size >= (size_t)17603808 * sizeof(int);

    dim3 blk256(256);
    dim3 blk512(512);
    dim3 blk1024(1024);

    if (ext) {
        int*   cnt2     = ws_i + 9002944;
        int*   off2     = ws_i + 9053120;
        int*   csum2    = ws_i + 9103296;
        int*   bbase2   = ws_i + 9103552;
        int2*  sc       = (int2*)(ws_i + 9103808);
        float* Ag       = (float*)(ws_i + 11103808);
        int*   node_cnt = ws_i + 17503808;

        zeroN    <<<(NG_ + 1023) / 1024, blk1024, 0, stream>>>(node_cnt);
        phaseA_f <<<NBLK, blk1024, 0, stream>>>(dst, cand, cnt_mat, cnt2, node_cnt);
        phaseB1_f<<<2 * NBUCK, blk256, 0, stream>>>(cnt_mat, cnt2, off_mat, off2,
                                                    colsum, csum2);
        phaseB2_f<<<1, blk256, 0, stream>>>(colsum, csum2, bbase, bbase2,
                                            wu, bu, wa, ba, wprep);
        scanN    <<<NBUCK, blk512, 0, stream>>>(node_cnt, bbase, node_off);
        phaseC_f <<<NBLK, blk1024, 0, stream>>>(src, dst, off_mat, bbase,
                                                cand, off2, bbase2, pairs, sc);
        phaseD2  <<<NBUCK, blk1024, 0, stream>>>(bbase, node_off, pairs, csr_src);
        conv1_csr<<<3125, blk256, 0, stream>>>(node_off, csr_src, x, w1_rel, w1_root, b1, h1);
        conv2_ag16<<<6250, blk256, 0, stream>>>(node_off, csr_src, h1, w2_rel, w2_root, b2,
                                                wa, wprep, Ag);
        final_mlp7<<<(C_CNT + 255) / 256, blk256, 0, stream>>>(sc, Ag, x, wprep, wb, bb, out);
    } else {
        int*   cnt2   = ws_i;                     // overlay cnt_mat
        int*   off2   = ws_i + 50176;             // overlay off_mat
        int*   csum2  = ws_i + 100352;            // overlay colsum
        int*   bbase2 = ws_i + 100608;            // overlay bbase
        int2*  sc     = (int2*)(ws_i + 6602944);  // overlay h1+h2
        float* Ag     = (float*)(ws_i + 202944);  // overlay pairs+csr_src

        prep_kernel<<<1, 64, 0, stream>>>(wu, bu, wa, ba, wprep);
        phaseA <<<NBLK, blk256, 0, stream>>>(dst, cnt_mat);
        phaseB1<<<NBUCK, blk256, 0, stream>>>(cnt_mat, off_mat, colsum);
        phaseB2<<<1, blk256, 0, stream>>>(colsum, bbase);
        phaseC <<<NBLK, blk256, 0, stream>>>(src, dst, off_mat, bbase, pairs);
        phaseD <<<NBUCK, blk1024, 0, stream>>>(bbase, pairs, csr_src, node_off);
        conv1_csr<<<3125, blk256, 0, stream>>>(node_off, csr_src, x, w1_rel, w1_root, b1, h1);
        conv2_csr<<<3125, blk256, 0, stream>>>(node_off, csr_src, h1, w2_rel, w2_root, b2, h2);
        precompA<<<(NG_ + 255) / 256, blk256, 0, stream>>>(h2, wa, wprep, Ag);
        candA <<<CBLK, blk256, 0, stream>>>(cand, cnt2);
        candB1<<<NBUCK, blk256, 0, stream>>>(cnt2, off2, csum2);
        candB2<<<1, blk256, 0, stream>>>(csum2, bbase2);
        candC <<<CBLK, blk256, 0, stream>>>(cand, off2, bbase2, sc);
        final_mlp7<<<(C_CNT + 255) / 256, blk256, 0, stream>>>(sc, Ag, x, wprep, wb, bb, out);
    }
}

// Round 15
// 244.539 us; speedup vs baseline: 1.5574x; 1.5574x over previous
//
#include <hip/hip_runtime.h>

#define N_TOT  200000
#define NG_    100000
#define NU_    100000
#define E_CNT  3200000
#define C_CNT  1000000

#define NBUCK  196        // ceil(NG_/512): bucket k covers nodes [k*512, k*512+512)
#define NBLK   256        // edge chunks
#define CHUNK  12500      // E_CNT / NBLK exactly

// fallback (round-5) candidate chunking
#define CBLK   250
#define CCHUNK 4000
// ext (fused) candidate chunking: 256 chunks of 3907 (last block short)
#define CCH_E  3907

// phaseD LDS staging capacity (bucket mean 16327, std ~128 -> +12 sigma)
#define DCAP   17920

// NOTE (r14 lesson): scattered GLOBAL atomics -- even fire-and-forget -- cost
// ~100 MB write amplification / ~110 us for 3.2M ops (non-coherent per-XCD L2s
// force RMW at the fabric coherence point). Only LDS atomics are cheap here.

// ======================= ext-path fused kernels =======================

// ---- phaseA_f: edge histogram + candidate histogram; 1024 thr (16 waves/CU) ----
__global__ __launch_bounds__(1024) void phaseA_f(const int* __restrict__ dst,
                                                 const int* __restrict__ cand,
                                                 int* __restrict__ cnt_mat,
                                                 int* __restrict__ cnt2) {
    __shared__ int hcnt[NBUCK];
    int t = threadIdx.x;
    if (t < NBUCK) hcnt[t] = 0;
    __syncthreads();
    int beg = blockIdx.x * CHUNK, end = beg + CHUNK;
    for (int e = beg + t; e < end; e += 1024)
        atomicAdd(&hcnt[dst[e] >> 9], 1);
    __syncthreads();
    if (t < NBUCK) { cnt_mat[blockIdx.x * NBUCK + t] = hcnt[t]; hcnt[t] = 0; }
    __syncthreads();
    int cbeg = blockIdx.x * CCH_E;
    int cend = min(cbeg + CCH_E, C_CNT);
    for (int e = cbeg + t; e < cend; e += 1024)
        atomicAdd(&hcnt[cand[2 * e] >> 9], 1);
    __syncthreads();
    if (t < NBUCK) cnt2[blockIdx.x * NBUCK + t] = hcnt[t];
}

// ---- phaseB1_f: 392 blocks; k<196 -> edge column scan, else cand column ----
__global__ __launch_bounds__(256) void phaseB1_f(const int* __restrict__ cnt_mat,
                                                 const int* __restrict__ cnt2,
                                                 int* __restrict__ off_mat,
                                                 int* __restrict__ off2,
                                                 int* __restrict__ colsum,
                                                 int* __restrict__ csum2) {
    __shared__ int s[256];
    int t = threadIdx.x;
    int k = blockIdx.x % NBUCK;
    bool is_cand = blockIdx.x >= NBUCK;
    const int* cm = is_cand ? cnt2 : cnt_mat;
    int v = cm[t * NBUCK + k];
    s[t] = v;
    __syncthreads();
    for (int off = 1; off < 256; off <<= 1) {
        int u = (t >= off) ? s[t - off] : 0;
        __syncthreads();
        s[t] += u;
        __syncthreads();
    }
    int* om = is_cand ? off2 : off_mat;
    om[t * NBUCK + k] = s[t] - v;
    if (t == 255) (is_cand ? csum2 : colsum)[k] = s[255];
}

// ---- phaseB2_f: both bucket-total scans + weight-prep fold ----
// wprep layout (floats): wT16[1024], wc0[64]@1024, wc1[64]@1088, bc[64]@1152
__global__ __launch_bounds__(256) void phaseB2_f(const int* __restrict__ colsum,
                                                 const int* __restrict__ csum2,
                                                 int* __restrict__ bbase,
                                                 int* __restrict__ bbase2,
                                                 const float* __restrict__ wu,
                                                 const float* __restrict__ bu,
                                                 const float* __restrict__ wa,
                                                 const float* __restrict__ ba,
                                                 float* __restrict__ wprep) {
    __shared__ int s[256];
    int t = threadIdx.x;
    int v = (t < NBUCK) ? colsum[t] : 0;
    s[t] = v;
    __syncthreads();
    for (int off = 1; off < 256; off <<= 1) {
        int u = (t >= off) ? s[t - off] : 0;
        __syncthreads();
        s[t] += u;
        __syncthreads();
    }
    if (t < NBUCK) bbase[t] = s[t] - v;
    if (t == NBUCK - 1) bbase[NBUCK] = s[t];
    __syncthreads();
    int v2 = (t < NBUCK) ? csum2[t] : 0;
    s[t] = v2;
    __syncthreads();
    for (int off = 1; off < 256; off <<= 1) {
        int u = (t >= off) ? s[t - off] : 0;
        __syncthreads();
        s[t] += u;
        __syncthreads();
    }
    if (t < NBUCK) bbase2[t] = s[t] - v2;
    if (t == NBUCK - 1) bbase2[NBUCK] = s[t];
    if (t < 64) {
        int j = t;
#pragma unroll
        for (int i = 0; i < 16; i++) wprep[j * 16 + i] = wa[i * 64 + j];
        float c0 = 0.f, c1 = 0.f, bc = ba[j];
#pragma unroll
        for (int k2 = 0; k2 < 16; k2++) {
            float w = wa[(16 + k2) * 64 + j];
            c0 += wu[k2] * w;
            c1 += wu[16 + k2] * w;
            bc += bu[k2] * w;
        }
        wprep[1024 + j] = c0;
        wprep[1088 + j] = c1;
        wprep[1152 + j] = bc;
    }
}

// ---- phaseC_f: edge + candidate bucket-scatter; 1024 thr (16 waves/CU) ----
// cand packing: w0 = g | (u<<17); w1 = (u>>15) | (idx<<2)
__global__ __launch_bounds__(1024) void phaseC_f(const int* __restrict__ src,
                                                 const int* __restrict__ dst,
                                                 const int* __restrict__ off_mat,
                                                 const int* __restrict__ bbase,
                                                 const int* __restrict__ cand,
                                                 const int* __restrict__ off2,
                                                 const int* __restrict__ bbase2,
                                                 int* __restrict__ pairs,
                                                 int2* __restrict__ sc) {
    __shared__ int loc[NBUCK];
    int t = threadIdx.x;
    if (t < NBUCK) loc[t] = bbase[t] + off_mat[blockIdx.x * NBUCK + t];
    __syncthreads();
    int beg = blockIdx.x * CHUNK, end = beg + CHUNK;
    for (int e = beg + t; e < end; e += 1024) {
        int d = dst[e], s = src[e];
        int k = d >> 9;
        int pos = atomicAdd(&loc[k], 1);
        pairs[pos] = (s << 9) | (d & 511);
    }
    __syncthreads();
    if (t < NBUCK) loc[t] = bbase2[t] + off2[blockIdx.x * NBUCK + t];
    __syncthreads();
    int cbeg = blockIdx.x * CCH_E;
    int cend = min(cbeg + CCH_E, C_CNT);
    for (int e = cbeg + t; e < cend; e += 1024) {
        int g = cand[2 * e], u = cand[2 * e + 1];
        int k = g >> 9;
        int pos = atomicAdd(&loc[k], 1);
        int w0 = g | (u << 17);
        int w1 = (int)(((unsigned)u >> 15) | ((unsigned)e << 2));
        sc[pos] = make_int2(w0, w1);
    }
}

// ======================= fallback (round-5) kernels =======================

__global__ __launch_bounds__(256) void phaseA(const int* __restrict__ dst,
                                              int* __restrict__ cnt_mat) {
    __shared__ int hcnt[NBUCK];
    int t = threadIdx.x;
    if (t < NBUCK) hcnt[t] = 0;
    __syncthreads();
    int beg = blockIdx.x * CHUNK, end = beg + CHUNK;
    for (int e = beg + t; e < end; e += 256)
        atomicAdd(&hcnt[dst[e] >> 9], 1);
    __syncthreads();
    if (t < NBUCK) cnt_mat[blockIdx.x * NBUCK + t] = hcnt[t];
}

__global__ __launch_bounds__(256) void phaseB1(const int* __restrict__ cnt_mat,
                                               int* __restrict__ off_mat,
                                               int* __restrict__ colsum) {
    __shared__ int s[256];
    int t = threadIdx.x;
    int k = blockIdx.x;
    int v = cnt_mat[t * NBUCK + k];
    s[t] = v;
    __syncthreads();
    for (int off = 1; off < 256; off <<= 1) {
        int u = (t >= off) ? s[t - off] : 0;
        __syncthreads();
        s[t] += u;
        __syncthreads();
    }
    off_mat[t * NBUCK + k] = s[t] - v;
    if (t == 255) colsum[k] = s[255];
}

__global__ __launch_bounds__(256) void phaseB2(const int* __restrict__ colsum,
                                               int* __restrict__ bbase) {
    __shared__ int s[256];
    int t = threadIdx.x;
    int v = (t < NBUCK) ? colsum[t] : 0;
    s[t] = v;
    __syncthreads();
    for (int off = 1; off < 256; off <<= 1) {
        int u = (t >= off) ? s[t - off] : 0;
        __syncthreads();
        s[t] += u;
        __syncthreads();
    }
    if (t < NBUCK) bbase[t] = s[t] - v;
    if (t == NBUCK - 1) bbase[NBUCK] = s[t];
}

__global__ __launch_bounds__(256) void phaseC(const int* __restrict__ src,
                                              const int* __restrict__ dst,
                                              const int* __restrict__ off_mat,
                                              const int* __restrict__ bbase,
                                              int* __restrict__ pairs) {
    __shared__ int loc[NBUCK];
    int t = threadIdx.x;
    if (t < NBUCK) loc[t] = bbase[t] + off_mat[blockIdx.x * NBUCK + t];
    __syncthreads();
    int beg = blockIdx.x * CHUNK, end = beg + CHUNK;
    for (int e = beg + t; e < end; e += 256) {
        int d = dst[e], s = src[e];
        int k = d >> 9;
        int pos = atomicAdd(&loc[k], 1);
        pairs[pos] = (s << 9) | (d & 511);
    }
}

__global__ void prep_kernel(const float* __restrict__ wu,
                            const float* __restrict__ bu,
                            const float* __restrict__ wa,
                            const float* __restrict__ ba,
                            float* __restrict__ wprep) {
    int j = threadIdx.x;   // 64 threads
#pragma unroll
    for (int i = 0; i < 16; i++) wprep[j * 16 + i] = wa[i * 64 + j];
    float c0 = 0.f, c1 = 0.f, bc = ba[j];
#pragma unroll
    for (int k = 0; k < 16; k++) {
        float w = wa[(16 + k) * 64 + j];
        c0 += wu[k] * w;
        c1 += wu[16 + k] * w;
        bc += bu[k] * w;
    }
    wprep[1024 + j] = c0;
    wprep[1088 + j] = c1;
    wprep[1152 + j] = bc;
}

__global__ __launch_bounds__(256) void candA(const int* __restrict__ cand,
                                             int* __restrict__ cnt2) {
    __shared__ int hcnt[NBUCK];
    int t = threadIdx.x;
    if (t < NBUCK) hcnt[t] = 0;
    __syncthreads();
    int beg = blockIdx.x * CCHUNK, end = beg + CCHUNK;
    for (int e = beg + t; e < end; e += 256)
        atomicAdd(&hcnt[cand[2 * e] >> 9], 1);
    __syncthreads();
    if (t < NBUCK) cnt2[blockIdx.x * NBUCK + t] = hcnt[t];
}

__global__ __launch_bounds__(256) void candB1(const int* __restrict__ cnt2,
                                              int* __restrict__ off2,
                                              int* __restrict__ csum2) {
    __shared__ int s[256];
    int t = threadIdx.x;
    int k = blockIdx.x;
    int v = (t < CBLK) ? cnt2[t * NBUCK + k] : 0;
    s[t] = v;
    __syncthreads();
    for (int off = 1; off < 256; off <<= 1) {
        int u = (t >= off) ? s[t - off] : 0;
        __syncthreads();
        s[t] += u;
        __syncthreads();
    }
    if (t < CBLK) off2[t * NBUCK + k] = s[t] - v;
    if (t == 255) csum2[k] = s[255];
}

__global__ __launch_bounds__(256) void candB2(const int* __restrict__ csum2,
                                              int* __restrict__ bbase2) {
    __shared__ int s[256];
    int t = threadIdx.x;
    int v = (t < NBUCK) ? csum2[t] : 0;
    s[t] = v;
    __syncthreads();
    for (int off = 1; off < 256; off <<= 1) {
        int u = (t >= off) ? s[t - off] : 0;
        __syncthreads();
        s[t] += u;
        __syncthreads();
    }
    if (t < NBUCK) bbase2[t] = s[t] - v;
    if (t == NBUCK - 1) bbase2[NBUCK] = s[t];
}

__global__ __launch_bounds__(256) void candC(const int* __restrict__ cand,
                                             const int* __restrict__ off2,
                                             const int* __restrict__ bbase2,
                                             int2* __restrict__ sc) {
    __shared__ int loc[NBUCK];
    int t = threadIdx.x;
    if (t < NBUCK) loc[t] = bbase2[t] + off2[blockIdx.x * NBUCK + t];
    __syncthreads();
    int beg = blockIdx.x * CCHUNK, end = beg + CCHUNK;
    for (int e = beg + t; e < end; e += 256) {
        int g = cand[2 * e], u = cand[2 * e + 1];
        int k = g >> 9;
        int pos = atomicAdd(&loc[k], 1);
        int w0 = g | (u << 17);
        int w1 = (int)(((unsigned)u >> 15) | ((unsigned)e << 2));
        sc[pos] = make_int2(w0, w1);
    }
}

// ======================= shared pipeline kernels =======================

// ---- phaseD: per-bucket counting sort; pairs staged in LDS on pass 1 ----
// Bucket size ~16327 +/- 128; DCAP=17920 is +12 sigma. i >= DCAP falls back
// to the global read (correct for any distribution).
__global__ __launch_bounds__(1024) void phaseD(const int* __restrict__ bbase,
                                               const int* __restrict__ pairs,
                                               int* __restrict__ csr_src,
                                               int* __restrict__ node_off) {
    __shared__ int cnt[512], scn[512], base[512];
    __shared__ int lpairs[DCAP];   // 70 KB; total ~78 KB (1 block/CU, grid=196)
    int t = threadIdx.x, k = blockIdx.x;
    if (t < 512) cnt[t] = 0;
    __syncthreads();
    int beg = bbase[k], end = bbase[k + 1];
    int len = end - beg;
    for (int i = t; i < len; i += 1024) {
        int p = pairs[beg + i];
        if (i < DCAP) lpairs[i] = p;
        atomicAdd(&cnt[p & 511], 1);
    }
    __syncthreads();
    if (t < 512) scn[t] = cnt[t];
    __syncthreads();
    for (int off = 1; off < 512; off <<= 1) {
        int v = 0;
        if (t < 512 && t >= off) v = scn[t - off];
        __syncthreads();
        if (t < 512) scn[t] += v;
        __syncthreads();
    }
    if (t < 512) {
        int bse = beg + scn[t] - cnt[t];
        base[t] = bse;
        node_off[(k << 9) + t] = bse;        // bucket 195 bins >= 160 empty,
                                             // so node_off[100000] == E_CNT.
    }
    __syncthreads();
    for (int i = t; i < len; i += 1024) {
        int p = (i < DCAP) ? lpairs[i] : pairs[beg + i];
        int pos = atomicAdd(&base[p & 511], 1);
        csr_src[pos] = p >> 9;
    }
}

// ---- conv1: CSR register aggregation, 8 lanes/node, 4-deep load pipeline ----
// avg degree 32 -> the whole node's gathers are in flight in one iteration.
__global__ __launch_bounds__(256) void conv1_csr(const int* __restrict__ node_off,
                                                 const int* __restrict__ csr_src,
                                                 const float* __restrict__ x,
                                                 const float* __restrict__ w_rel,
                                                 const float* __restrict__ w_root,
                                                 const float* __restrict__ b,
                                                 float* __restrict__ h1) {
    int t = threadIdx.x;
    int n = blockIdx.x * 32 + (t >> 3);
    int l = t & 7;
    int beg = node_off[n], end = node_off[n + 1];
    float a0 = 0.f, a1 = 0.f, b0 = 0.f, b1v = 0.f;
    float c0 = 0.f, c1 = 0.f, d0 = 0.f, d1 = 0.f;
    int e = beg + l;
    for (; e + 24 < end; e += 32) {
        int s0 = csr_src[e];
        int s1 = csr_src[e + 8];
        int s2 = csr_src[e + 16];
        int s3 = csr_src[e + 24];
        float2 v0 = *(const float2*)(x + 2 * s0);   // 4 independent loads in flight
        float2 v1 = *(const float2*)(x + 2 * s1);
        float2 v2 = *(const float2*)(x + 2 * s2);
        float2 v3 = *(const float2*)(x + 2 * s3);
        a0 += v0.x; a1 += v0.y;
        b0 += v1.x; b1v += v1.y;
        c0 += v2.x; c1 += v2.y;
        d0 += v3.x; d1 += v3.y;
    }
    for (; e < end; e += 8) {
        int s0 = csr_src[e];
        float2 v0 = *(const float2*)(x + 2 * s0);
        a0 += v0.x; a1 += v0.y;
    }
    a0 += b0 + c0 + d0;
    a1 += b1v + c1 + d1;
#pragma unroll
    for (int d = 1; d < 8; d <<= 1) {
        a0 += __shfl_xor(a0, d, 64);
        a1 += __shfl_xor(a1, d, 64);
    }
    float2 xn = *(const float2*)(x + 2 * n);
    float v = a0 * w_rel[l] + a1 * w_rel[8 + l]
            + xn.x * w_root[l] + xn.y * w_root[8 + l] + b[l];
    h1[8 * n + l] = fmaxf(v, 0.f);
}

// ---- conv2_ag16: conv2 + precompA fused, 16 lanes/node, paired-line gather,
//      4-deep load pipeline (each lane-pair keeps 4 independent h1 rows in flight;
//      avg degree 32 means one main-loop iteration covers the whole node) ----
__global__ __launch_bounds__(256) void conv2_ag16(const int* __restrict__ node_off,
                                                  const int* __restrict__ csr_src,
                                                  const float* __restrict__ h1,
                                                  const float* __restrict__ w_rel,
                                                  const float* __restrict__ w_root,
                                                  const float* __restrict__ b,
                                                  const float* __restrict__ wa,
                                                  const float* __restrict__ wprep,
                                                  float* __restrict__ Ag) {
    __shared__ float sh[16][17];   // h2 staging, +1 pad
    int t = threadIdx.x;
    int g = t >> 4, l = t & 15;    // 16 nodes/block, 16 lanes/node
    int pr = l & 1, pe = l >> 1;   // pr: row half, pe: edge slot (0..7)
    int n = blockIdx.x * 16 + g;   // grid 6250*16 == 100000 exactly
    int beg = node_off[n], end = node_off[n + 1];
    float4 a4 = make_float4(0.f, 0.f, 0.f, 0.f);
    float4 b4 = make_float4(0.f, 0.f, 0.f, 0.f);
    float4 c4 = make_float4(0.f, 0.f, 0.f, 0.f);
    float4 d4 = make_float4(0.f, 0.f, 0.f, 0.f);
    int e = beg + pe;
    for (; e + 24 < end; e += 32) {
        int s0 = csr_src[e];
        int s1 = csr_src[e + 8];
        int s2 = csr_src[e + 16];
        int s3 = csr_src[e + 24];
        float4 v0 = *(const float4*)(h1 + 8 * s0 + 4 * pr);
        float4 v1 = *(const float4*)(h1 + 8 * s1 + 4 * pr);
        float4 v2 = *(const float4*)(h1 + 8 * s2 + 4 * pr);
        float4 v3 = *(const float4*)(h1 + 8 * s3 + 4 * pr);
        a4.x += v0.x; a4.y += v0.y; a4.z += v0.z; a4.w += v0.w;
        b4.x += v1.x; b4.y += v1.y; b4.z += v1.z; b4.w += v1.w;
        c4.x += v2.x; c4.y += v2.y; c4.z += v2.z; c4.w += v2.w;
        d4.x += v3.x; d4.y += v3.y; d4.z += v3.z; d4.w += v3.w;
    }
    for (; e < end; e += 8) {
        int s0 = csr_src[e];
        float4 v0 = *(const float4*)(h1 + 8 * s0 + 4 * pr);
        a4.x += v0.x; a4.y += v0.y; a4.z += v0.z; a4.w += v0.w;
    }
    a4.x += b4.x + c4.x + d4.x;
    a4.y += b4.y + c4.y + d4.y;
    a4.z += b4.z + c4.z + d4.z;
    a4.w += b4.w + c4.w + d4.w;
    // butterfly over edge slots (xor 2,4,8 stays within the 16-lane group):
#pragma unroll
    for (int d = 2; d < 16; d <<= 1) {
        a4.x += __shfl_xor(a4.x, d);
        a4.y += __shfl_xor(a4.y, d);
        a4.z += __shfl_xor(a4.z, d);
        a4.w += __shfl_xor(a4.w, d);
    }
    // exchange halves: every lane assembles the full 8-dim aggregate
    float o0 = __shfl_xor(a4.x, 1), o1 = __shfl_xor(a4.y, 1);
    float o2 = __shfl_xor(a4.z, 1), o3 = __shfl_xor(a4.w, 1);
    float agg[8];
    if (pr == 0) {
        agg[0] = a4.x; agg[1] = a4.y; agg[2] = a4.z; agg[3] = a4.w;
        agg[4] = o0;   agg[5] = o1;   agg[6] = o2;   agg[7] = o3;
    } else {
        agg[0] = o0;   agg[1] = o1;   agg[2] = o2;   agg[3] = o3;
        agg[4] = a4.x; agg[5] = a4.y; agg[6] = a4.z; agg[7] = a4.w;
    }
    // root term: all 16 lanes read node n's row (1-2 lines, broadcast)
    const float4* hp = (const float4*)(h1 + 8 * n);
    float4 t0 = hp[0], t1 = hp[1];
    float hn[8] = {t0.x, t0.y, t0.z, t0.w, t1.x, t1.y, t1.z, t1.w};
    // h2 dim c = l (one per lane)
    {
        int c = l;
        float v = b[c];
#pragma unroll
        for (int j = 0; j < 8; j++)
            v += agg[j] * w_rel[j * 16 + c] + hn[j] * w_root[j * 16 + c];
        sh[g][c] = fmaxf(v, 0.f);
    }
    __syncthreads();
    // A-row: lane l computes j in [4l, 4l+4); 16 lanes x 16B = 256B coalesced
    float4 a = *(const float4*)(wprep + 1152 + 4 * l);
#pragma unroll
    for (int i = 0; i < 16; i++) {
        float hi = sh[g][i];
        float4 w = *(const float4*)(wa + i * 64 + 4 * l);
        a.x += hi * w.x; a.y += hi * w.y; a.z += hi * w.z; a.w += hi * w.w;
    }
    *(float4*)(Ag + 64 * n + 4 * l) = a;
}

// ---- fallback: conv2 writing h2 + separate precompA (Ag overlays csr there) ----
__global__ __launch_bounds__(256) void conv2_csr(const int* __restrict__ node_off,
                                                 const int* __restrict__ csr_src,
                                                 const float* __restrict__ h1,
                                                 const float* __restrict__ w_rel,
                                                 const float* __restrict__ w_root,
                                                 const float* __restrict__ b,
                                                 float* __restrict__ h2) {
    int t = threadIdx.x;
    int n = blockIdx.x * 32 + (t >> 3);
    int l = t & 7;
    int beg = node_off[n], end = node_off[n + 1];
    float acc[8] = {0.f, 0.f, 0.f, 0.f, 0.f, 0.f, 0.f, 0.f};
    for (int e = beg + l; e < end; e += 8) {
        int s = csr_src[e];
        const float4* hp = (const float4*)(h1 + 8 * s);
        float4 v0 = hp[0], v1 = hp[1];
        acc[0] += v0.x; acc[1] += v0.y; acc[2] += v0.z; acc[3] += v0.w;
        acc[4] += v1.x; acc[5] += v1.y; acc[6] += v1.z; acc[7] += v1.w;
    }
#pragma unroll
    for (int d = 1; d < 8; d <<= 1)
#pragma unroll
        for (int j = 0; j < 8; j++)
            acc[j] += __shfl_xor(acc[j], d, 64);
    const float4* hp = (const float4*)(h1 + 8 * n);
    float4 t0 = hp[0], t1 = hp[1];
    float hn[8] = {t0.x, t0.y, t0.z, t0.w, t1.x, t1.y, t1.z, t1.w};
#pragma unroll
    for (int cc = 0; cc < 2; cc++) {
        int c = l + 8 * cc;
        float v = b[c];
#pragma unroll
        for (int j = 0; j < 8; j++)
            v += acc[j] * w_rel[j * 16 + c] + hn[j] * w_root[j * 16 + c];
        h2[16 * n + c] = fmaxf(v, 0.f);
    }
}

__global__ __launch_bounds__(256) void precompA(const float* __restrict__ h2,
                                                const float* __restrict__ wa,
                                                const float* __restrict__ wprep,
                                                float* __restrict__ Ag) {
    int g = blockIdx.x * 256 + threadIdx.x;
    if (g >= NG_) return;
    float h[16];
    const float4* hp = (const float4*)(h2 + 16 * g);
#pragma unroll
    for (int q = 0; q < 4; q++) {
        float4 v = hp[q];
        h[4*q] = v.x; h[4*q+1] = v.y; h[4*q+2] = v.z; h[4*q+3] = v.w;
    }
    float4* op = (float4*)(Ag + 64 * g);
#pragma unroll
    for (int q = 0; q < 16; q++) {
        float4 v;
        v.x = wprep[1152 + 4*q + 0];
        v.y = wprep[1152 + 4*q + 1];
        v.z = wprep[1152 + 4*q + 2];
        v.w = wprep[1152 + 4*q + 3];
#pragma unroll
        for (int i = 0; i < 16; i++) {
            float hi = h[i];
            v.x += hi * wa[i*64 + 4*q + 0];
            v.y += hi * wa[i*64 + 4*q + 1];
            v.z += hi * wa[i*64 + 4*q + 2];
            v.w += hi * wa[i*64 + 4*q + 3];
        }
        op[q] = v;
    }
}

// ---- final MLP v7: 8 lanes per candidate, coalesced 256B row reads ----
__global__ __launch_bounds__(256) void final_mlp7(const int2* __restrict__ sc,
                                                  const float* __restrict__ Ag,
                                                  const float* __restrict__ x,
                                                  const float* __restrict__ wprep,
                                                  const float* __restrict__ wb,
                                                  const float* __restrict__ bb,
                                                  float* __restrict__ out) {
    // m204 bijective chunked swizzle (keep sorted candidates XCD-local)
    int nwg = gridDim.x;
    int xcd = blockIdx.x & 7, pos = blockIdx.x >> 3;
    int q = nwg >> 3, r = nwg & 7;
    int wg = (xcd < r ? xcd * (q + 1) : r * (q + 1) + (xcd - r) * q) + pos;

    int t = threadIdx.x;
    int l = t & 7;
    int grp = t >> 3;
    float4 c0lo = *(const float4*)(wprep + 1024 + 4 * l);
    float4 c0hi = *(const float4*)(wprep + 1024 + 32 + 4 * l);
    float4 c1lo = *(const float4*)(wprep + 1088 + 4 * l);
    float4 c1hi = *(const float4*)(wprep + 1088 + 32 + 4 * l);
    float4 wblo = *(const float4*)(wb + 4 * l);
    float4 wbhi = *(const float4*)(wb + 32 + 4 * l);
    float bb0 = bb[0];

    int base = wg * 256;
#pragma unroll 2
    for (int it = 0; it < 8; ++it) {
        int c = base + it * 32 + grp;
        if (c < C_CNT) {
            int2 w = sc[c];
            unsigned w0 = (unsigned)w.x, w1 = (unsigned)w.y;
            int g   = (int)(w0 & 0x1FFFFu);
            int u   = (int)((w0 >> 17) | ((w1 & 3u) << 15));
            int idx = (int)(w1 >> 2);
            float2 xv = *(const float2*)(x + 2 * (NG_ + u));
            const float* rp = Ag + 64 * g;
            float4 alo = *(const float4*)(rp + 4 * l);
            float4 ahi = *(const float4*)(rp + 32 + 4 * l);
            float acc;
            {
                float v0 = alo.x + xv.x * c0lo.x + xv.y * c1lo.x;
                float v1 = alo.y + xv.x * c0lo.y + xv.y * c1lo.y;
                float v2 = alo.z + xv.x * c0lo.z + xv.y * c1lo.z;
                float v3 = alo.w + xv.x * c0lo.w + xv.y * c1lo.w;
                acc  = fmaxf(v0, 0.f) * wblo.x;
                acc += fmaxf(v1, 0.f) * wblo.y;
                acc += fmaxf(v2, 0.f) * wblo.z;
                acc += fmaxf(v3, 0.f) * wblo.w;
            }
            {
                float v0 = ahi.x + xv.x * c0hi.x + xv.y * c1hi.x;
                float v1 = ahi.y + xv.x * c0hi.y + xv.y * c1hi.y;
                float v2 = ahi.z + xv.x * c0hi.z + xv.y * c1hi.z;
                float v3 = ahi.w + xv.x * c0hi.w + xv.y * c1hi.w;
                acc += fmaxf(v0, 0.f) * wbhi.x;
                acc += fmaxf(v1, 0.f) * wbhi.y;
                acc += fmaxf(v2, 0.f) * wbhi.z;
                acc += fmaxf(v3, 0.f) * wbhi.w;
            }
            acc += __shfl_xor(acc, 1);
            acc += __shfl_xor(acc, 2);
            acc += __shfl_xor(acc, 4);
            if (l == 0) out[idx] = acc + bb0;
        }
    }
}

// ======================= launch =======================

extern "C" void kernel_launch(void* const* d_in, const int* in_sizes, int n_in,
                              void* d_out, int out_size, void* d_ws, size_t ws_size,
                              hipStream_t stream) {
    const float* x      = (const float*)d_in[0];
    const int*   cand   = (const int*)d_in[2];
    const int*   edges  = (const int*)d_in[3];   // [2, E]: src then dst
    const float* w1_rel = (const float*)d_in[4];
    const float* w1_root= (const float*)d_in[5];
    const float* b1     = (const float*)d_in[6];
    const float* w2_rel = (const float*)d_in[7];
    const float* w2_root= (const float*)d_in[8];
    const float* b2     = (const float*)d_in[9];
    const float* wu     = (const float*)d_in[10];
    const float* bu     = (const float*)d_in[11];
    const float* wa     = (const float*)d_in[12];
    const float* ba     = (const float*)d_in[13];
    const float* wb     = (const float*)d_in[14];
    const float* bb     = (const float*)d_in[15];
    float* out = (float*)d_out;

    const int* src = edges;
    const int* dst = edges + E_CNT;

    // Base layout (int units), 9,002,944 ints = 36.0 MB:
    //   cnt_mat  [0         .. 50,176)
    //   off_mat  [50,176    .. 100,352)
    //   colsum   [100,352   .. 100,548)
    //   bbase    [100,608   .. 100,805)
    //   node_off [100,864   .. 201,728)
    //   wprep    [201,728   .. 202,944)
    //   pairs    [202,944   .. 3,402,944)
    //   csr_src  [3,402,944 .. 6,602,944)
    //   h1 (f)   [6,602,944 .. 7,402,944)
    //   h2 (f)   [7,402,944 .. 9,002,944)   (fallback only)
    // EXT extras (needs 17,503,808 ints = 70.0 MB; harness fill showed 256 MiB):
    //   cnt2   [9,002,944 .. 9,053,120)
    //   off2   [9,053,120 .. 9,103,296)
    //   csum2  [9,103,296 .. 9,103,492)  pad-> 9,103,552
    //   bbase2 [9,103,552 .. 9,103,749)  pad-> 9,103,808
    //   sc     [9,103,808 .. 11,103,808)  (1M int2, 8B-aligned)
    //   Ag     [11,103,808 .. 17,503,808) (6.4M floats, FRESH: conv2_ag16 still
    //           reads csr_src so the old csr overlay is illegal in ext path)
    // FALLBACK (round-5 proven): cnt2/off2/csum2/bbase2 overlay cnt_mat/off_mat/
    //   colsum/bbase; Ag overlays pairs+csr; sc overlays h1+h2; sort after precompA.
    int* ws_i = (int*)d_ws;
    int*   cnt_mat  = ws_i;
    int*   off_mat  = ws_i + 50176;
    int*   colsum   = ws_i + 100352;
    int*   bbase    = ws_i + 100608;
    int*   node_off = ws_i + 100864;
    float* wprep    = (float*)(ws_i + 201728);
    int*   pairs    = ws_i + 202944;
    int*   csr_src  = ws_i + 3402944;
    float* h1       = (float*)(ws_i + 6602944);
    float* h2       = (float*)(ws_i + 7402944);

    bool ext = ws_size >= (size_t)17503808 * sizeof(int);

    dim3 blk256(256);
    dim3 blk1024(1024);

    if (ext) {
        int*   cnt2   = ws_i + 9002944;
        int*   off2   = ws_i + 9053120;
        int*   csum2  = ws_i + 9103296;
        int*   bbase2 = ws_i + 9103552;
        int2*  sc     = (int2*)(ws_i + 9103808);
        float* Ag     = (float*)(ws_i + 11103808);

        phaseA_f <<<NBLK, blk1024, 0, stream>>>(dst, cand, cnt_mat, cnt2);
        phaseB1_f<<<2 * NBUCK, blk256, 0, stream>>>(cnt_mat, cnt2, off_mat, off2,
                                                    colsum, csum2);
        phaseB2_f<<<1, blk256, 0, stream>>>(colsum, csum2, bbase, bbase2,
                                            wu, bu, wa, ba, wprep);
        phaseC_f <<<NBLK, blk1024, 0, stream>>>(src, dst, off_mat, bbase,
                                                cand, off2, bbase2, pairs, sc);
        phaseD <<<NBUCK, blk1024, 0, stream>>>(bbase, pairs, csr_src, node_off);
        conv1_csr<<<3125, blk256, 0, stream>>>(node_off, csr_src, x, w1_rel, w1_root, b1, h1);
        conv2_ag16<<<6250, blk256, 0, stream>>>(node_off, csr_src, h1, w2_rel, w2_root, b2,
                                                wa, wprep, Ag);
        final_mlp7<<<(C_CNT + 255) / 256, blk256, 0, stream>>>(sc, Ag, x, wprep, wb, bb, out);
    } else {
        int*   cnt2   = ws_i;                     // overlay cnt_mat
        int*   off2   = ws_i + 50176;             // overlay off_mat
        int*   csum2  = ws_i + 100352;            // overlay colsum
        int*   bbase2 = ws_i + 100608;            // overlay bbase
        int2*  sc     = (int2*)(ws_i + 6602944);  // overlay h1+h2
        float* Ag     = (float*)(ws_i + 202944);  // overlay pairs+csr_src

        prep_kernel<<<1, 64, 0, stream>>>(wu, bu, wa, ba, wprep);
        phaseA <<<NBLK, blk256, 0, stream>>>(dst, cnt_mat);
        phaseB1<<<NBUCK, blk256, 0, stream>>>(cnt_mat, off_mat, colsum);
        phaseB2<<<1, blk256, 0, stream>>>(colsum, bbase);
        phaseC <<<NBLK, blk256, 0, stream>>>(src, dst, off_mat, bbase, pairs);
        phaseD <<<NBUCK, blk1024, 0, stream>>>(bbase, pairs, csr_src, node_off);
        conv1_csr<<<3125, blk256, 0, stream>>>(node_off, csr_src, x, w1_rel, w1_root, b1, h1);
        conv2_csr<<<3125, blk256, 0, stream>>>(node_off, csr_src, h1, w2_rel, w2_root, b2, h2);
        precompA<<<(NG_ + 255) / 256, blk256, 0, stream>>>(h2, wa, wprep, Ag);
        candA <<<CBLK, blk256, 0, stream>>>(cand, cnt2);
        candB1<<<NBUCK, blk256, 0, stream>>>(cnt2, off2, csum2);
        candB2<<<1, blk256, 0, stream>>>(csum2, bbase2);
        candC <<<CBLK, blk256, 0, stream>>>(cand, off2, bbase2, sc);
        final_mlp7<<<(C_CNT + 255) / 256, blk256, 0, stream>>>(sc, Ag, x, wprep, wb, bb, out);
    }
}

// Round 16
// 239.666 us; speedup vs baseline: 1.5891x; 1.0203x over previous
//
#include <hip/hip_runtime.h>

#define N_TOT  200000
#define NG_    100000
#define NU_    100000
#define E_CNT  3200000
#define C_CNT  1000000

#define NBUCK  196        // ceil(NG_/512): bucket k covers nodes [k*512, k*512+512)
#define NBLK   256        // edge chunks
#define CHUNK  12500      // E_CNT / NBLK exactly

// fallback (round-5) candidate chunking
#define CBLK   250
#define CCHUNK 4000
// ext (fused) candidate chunking: 256 chunks of 3907 (last block short)
#define CCH_E  3907

// phaseD LDS staging capacity (bucket mean 16327, std ~128 -> +12 sigma)
#define DCAP   17920

// NOTE (r14 lesson): scattered GLOBAL atomics -- even fire-and-forget -- cost
// ~100 MB write amplification / ~110 us for 3.2M ops (non-coherent per-XCD L2s
// force RMW at the fabric coherence point). Only LDS atomics are cheap here.

// ======================= ext-path fused kernels =======================

// ---- phaseA_f: edge histogram + candidate histogram; 1024 thr (16 waves/CU);
//      int2-vectorized loads (2 edges / iteration) ----
__global__ __launch_bounds__(1024) void phaseA_f(const int* __restrict__ dst,
                                                 const int* __restrict__ cand,
                                                 int* __restrict__ cnt_mat,
                                                 int* __restrict__ cnt2) {
    __shared__ int hcnt[NBUCK];
    int t = threadIdx.x;
    if (t < NBUCK) hcnt[t] = 0;
    __syncthreads();
    // CHUNK = 12500 even; beg/2 = blockIdx*6250; dst 8B-aligned (E_CNT even).
    const int2* dst2 = (const int2*)dst;
    int hbeg = blockIdx.x * (CHUNK / 2);
    for (int i = t; i < CHUNK / 2; i += 1024) {
        int2 d = dst2[hbeg + i];
        atomicAdd(&hcnt[d.x >> 9], 1);
        atomicAdd(&hcnt[d.y >> 9], 1);
    }
    __syncthreads();
    if (t < NBUCK) { cnt_mat[blockIdx.x * NBUCK + t] = hcnt[t]; hcnt[t] = 0; }
    __syncthreads();
    const int2* cand2 = (const int2*)cand;
    int cbeg = blockIdx.x * CCH_E;
    int cend = min(cbeg + CCH_E, C_CNT);
    for (int e = cbeg + t; e < cend; e += 1024)
        atomicAdd(&hcnt[cand2[e].x >> 9], 1);   // vector load, use g only
    __syncthreads();
    if (t < NBUCK) cnt2[blockIdx.x * NBUCK + t] = hcnt[t];
}

// ---- phaseB1_f: 392 blocks; k<196 -> edge column scan, else cand column ----
__global__ __launch_bounds__(256) void phaseB1_f(const int* __restrict__ cnt_mat,
                                                 const int* __restrict__ cnt2,
                                                 int* __restrict__ off_mat,
                                                 int* __restrict__ off2,
                                                 int* __restrict__ colsum,
                                                 int* __restrict__ csum2) {
    __shared__ int s[256];
    int t = threadIdx.x;
    int k = blockIdx.x % NBUCK;
    bool is_cand = blockIdx.x >= NBUCK;
    const int* cm = is_cand ? cnt2 : cnt_mat;
    int v = cm[t * NBUCK + k];
    s[t] = v;
    __syncthreads();
    for (int off = 1; off < 256; off <<= 1) {
        int u = (t >= off) ? s[t - off] : 0;
        __syncthreads();
        s[t] += u;
        __syncthreads();
    }
    int* om = is_cand ? off2 : off_mat;
    om[t * NBUCK + k] = s[t] - v;
    if (t == 255) (is_cand ? csum2 : colsum)[k] = s[255];
}

// ---- phaseB2_f: both bucket-total scans + weight-prep fold ----
// wprep layout (floats): wT16[1024], wc0[64]@1024, wc1[64]@1088, bc[64]@1152
__global__ __launch_bounds__(256) void phaseB2_f(const int* __restrict__ colsum,
                                                 const int* __restrict__ csum2,
                                                 int* __restrict__ bbase,
                                                 int* __restrict__ bbase2,
                                                 const float* __restrict__ wu,
                                                 const float* __restrict__ bu,
                                                 const float* __restrict__ wa,
                                                 const float* __restrict__ ba,
                                                 float* __restrict__ wprep) {
    __shared__ int s[256];
    int t = threadIdx.x;
    int v = (t < NBUCK) ? colsum[t] : 0;
    s[t] = v;
    __syncthreads();
    for (int off = 1; off < 256; off <<= 1) {
        int u = (t >= off) ? s[t - off] : 0;
        __syncthreads();
        s[t] += u;
        __syncthreads();
    }
    if (t < NBUCK) bbase[t] = s[t] - v;
    if (t == NBUCK - 1) bbase[NBUCK] = s[t];
    __syncthreads();
    int v2 = (t < NBUCK) ? csum2[t] : 0;
    s[t] = v2;
    __syncthreads();
    for (int off = 1; off < 256; off <<= 1) {
        int u = (t >= off) ? s[t - off] : 0;
        __syncthreads();
        s[t] += u;
        __syncthreads();
    }
    if (t < NBUCK) bbase2[t] = s[t] - v2;
    if (t == NBUCK - 1) bbase2[NBUCK] = s[t];
    if (t < 64) {
        int j = t;
#pragma unroll
        for (int i = 0; i < 16; i++) wprep[j * 16 + i] = wa[i * 64 + j];
        float c0 = 0.f, c1 = 0.f, bc = ba[j];
#pragma unroll
        for (int k2 = 0; k2 < 16; k2++) {
            float w = wa[(16 + k2) * 64 + j];
            c0 += wu[k2] * w;
            c1 += wu[16 + k2] * w;
            bc += bu[k2] * w;
        }
        wprep[1024 + j] = c0;
        wprep[1088 + j] = c1;
        wprep[1152 + j] = bc;
    }
}

// ---- phaseC_f: edge + candidate bucket-scatter; 1024 thr (16 waves/CU);
//      int2-vectorized loads (2 edges / iteration) ----
// cand packing: w0 = g | (u<<17); w1 = (u>>15) | (idx<<2)
__global__ __launch_bounds__(1024) void phaseC_f(const int* __restrict__ src,
                                                 const int* __restrict__ dst,
                                                 const int* __restrict__ off_mat,
                                                 const int* __restrict__ bbase,
                                                 const int* __restrict__ cand,
                                                 const int* __restrict__ off2,
                                                 const int* __restrict__ bbase2,
                                                 int* __restrict__ pairs,
                                                 int2* __restrict__ sc) {
    __shared__ int loc[NBUCK];
    int t = threadIdx.x;
    if (t < NBUCK) loc[t] = bbase[t] + off_mat[blockIdx.x * NBUCK + t];
    __syncthreads();
    const int2* src2 = (const int2*)src;
    const int2* dst2 = (const int2*)dst;
    int hbeg = blockIdx.x * (CHUNK / 2);
    for (int i = t; i < CHUNK / 2; i += 1024) {
        int2 d = dst2[hbeg + i];
        int2 s = src2[hbeg + i];
        int k0 = d.x >> 9;
        int p0 = atomicAdd(&loc[k0], 1);
        pairs[p0] = (s.x << 9) | (d.x & 511);
        int k1 = d.y >> 9;
        int p1 = atomicAdd(&loc[k1], 1);
        pairs[p1] = (s.y << 9) | (d.y & 511);
    }
    __syncthreads();
    if (t < NBUCK) loc[t] = bbase2[t] + off2[blockIdx.x * NBUCK + t];
    __syncthreads();
    const int2* cand2 = (const int2*)cand;
    int cbeg = blockIdx.x * CCH_E;
    int cend = min(cbeg + CCH_E, C_CNT);
    for (int e = cbeg + t; e < cend; e += 1024) {
        int2 gu = cand2[e];
        int g = gu.x, u = gu.y;
        int k = g >> 9;
        int pos = atomicAdd(&loc[k], 1);
        int w0 = g | (u << 17);
        int w1 = (int)(((unsigned)u >> 15) | ((unsigned)e << 2));
        sc[pos] = make_int2(w0, w1);
    }
}

// ======================= fallback (round-5) kernels =======================

__global__ __launch_bounds__(256) void phaseA(const int* __restrict__ dst,
                                              int* __restrict__ cnt_mat) {
    __shared__ int hcnt[NBUCK];
    int t = threadIdx.x;
    if (t < NBUCK) hcnt[t] = 0;
    __syncthreads();
    int beg = blockIdx.x * CHUNK, end = beg + CHUNK;
    for (int e = beg + t; e < end; e += 256)
        atomicAdd(&hcnt[dst[e] >> 9], 1);
    __syncthreads();
    if (t < NBUCK) cnt_mat[blockIdx.x * NBUCK + t] = hcnt[t];
}

__global__ __launch_bounds__(256) void phaseB1(const int* __restrict__ cnt_mat,
                                               int* __restrict__ off_mat,
                                               int* __restrict__ colsum) {
    __shared__ int s[256];
    int t = threadIdx.x;
    int k = blockIdx.x;
    int v = cnt_mat[t * NBUCK + k];
    s[t] = v;
    __syncthreads();
    for (int off = 1; off < 256; off <<= 1) {
        int u = (t >= off) ? s[t - off] : 0;
        __syncthreads();
        s[t] += u;
        __syncthreads();
    }
    off_mat[t * NBUCK + k] = s[t] - v;
    if (t == 255) colsum[k] = s[255];
}

__global__ __launch_bounds__(256) void phaseB2(const int* __restrict__ colsum,
                                               int* __restrict__ bbase) {
    __shared__ int s[256];
    int t = threadIdx.x;
    int v = (t < NBUCK) ? colsum[t] : 0;
    s[t] = v;
    __syncthreads();
    for (int off = 1; off < 256; off <<= 1) {
        int u = (t >= off) ? s[t - off] : 0;
        __syncthreads();
        s[t] += u;
        __syncthreads();
    }
    if (t < NBUCK) bbase[t] = s[t] - v;
    if (t == NBUCK - 1) bbase[NBUCK] = s[t];
}

__global__ __launch_bounds__(256) void phaseC(const int* __restrict__ src,
                                              const int* __restrict__ dst,
                                              const int* __restrict__ off_mat,
                                              const int* __restrict__ bbase,
                                              int* __restrict__ pairs) {
    __shared__ int loc[NBUCK];
    int t = threadIdx.x;
    if (t < NBUCK) loc[t] = bbase[t] + off_mat[blockIdx.x * NBUCK + t];
    __syncthreads();
    int beg = blockIdx.x * CHUNK, end = beg + CHUNK;
    for (int e = beg + t; e < end; e += 256) {
        int d = dst[e], s = src[e];
        int k = d >> 9;
        int pos = atomicAdd(&loc[k], 1);
        pairs[pos] = (s << 9) | (d & 511);
    }
}

__global__ void prep_kernel(const float* __restrict__ wu,
                            const float* __restrict__ bu,
                            const float* __restrict__ wa,
                            const float* __restrict__ ba,
                            float* __restrict__ wprep) {
    int j = threadIdx.x;   // 64 threads
#pragma unroll
    for (int i = 0; i < 16; i++) wprep[j * 16 + i] = wa[i * 64 + j];
    float c0 = 0.f, c1 = 0.f, bc = ba[j];
#pragma unroll
    for (int k = 0; k < 16; k++) {
        float w = wa[(16 + k) * 64 + j];
        c0 += wu[k] * w;
        c1 += wu[16 + k] * w;
        bc += bu[k] * w;
    }
    wprep[1024 + j] = c0;
    wprep[1088 + j] = c1;
    wprep[1152 + j] = bc;
}

__global__ __launch_bounds__(256) void candA(const int* __restrict__ cand,
                                             int* __restrict__ cnt2) {
    __shared__ int hcnt[NBUCK];
    int t = threadIdx.x;
    if (t < NBUCK) hcnt[t] = 0;
    __syncthreads();
    int beg = blockIdx.x * CCHUNK, end = beg + CCHUNK;
    for (int e = beg + t; e < end; e += 256)
        atomicAdd(&hcnt[cand[2 * e] >> 9], 1);
    __syncthreads();
    if (t < NBUCK) cnt2[blockIdx.x * NBUCK + t] = hcnt[t];
}

__global__ __launch_bounds__(256) void candB1(const int* __restrict__ cnt2,
                                              int* __restrict__ off2,
                                              int* __restrict__ csum2) {
    __shared__ int s[256];
    int t = threadIdx.x;
    int k = blockIdx.x;
    int v = (t < CBLK) ? cnt2[t * NBUCK + k] : 0;
    s[t] = v;
    __syncthreads();
    for (int off = 1; off < 256; off <<= 1) {
        int u = (t >= off) ? s[t - off] : 0;
        __syncthreads();
        s[t] += u;
        __syncthreads();
    }
    if (t < CBLK) off2[t * NBUCK + k] = s[t] - v;
    if (t == 255) csum2[k] = s[255];
}

__global__ __launch_bounds__(256) void candB2(const int* __restrict__ csum2,
                                              int* __restrict__ bbase2) {
    __shared__ int s[256];
    int t = threadIdx.x;
    int v = (t < NBUCK) ? csum2[t] : 0;
    s[t] = v;
    __syncthreads();
    for (int off = 1; off < 256; off <<= 1) {
        int u = (t >= off) ? s[t - off] : 0;
        __syncthreads();
        s[t] += u;
        __syncthreads();
    }
    if (t < NBUCK) bbase2[t] = s[t] - v;
    if (t == NBUCK - 1) bbase2[NBUCK] = s[t];
}

__global__ __launch_bounds__(256) void candC(const int* __restrict__ cand,
                                             const int* __restrict__ off2,
                                             const int* __restrict__ bbase2,
                                             int2* __restrict__ sc) {
    __shared__ int loc[NBUCK];
    int t = threadIdx.x;
    if (t < NBUCK) loc[t] = bbase2[t] + off2[blockIdx.x * NBUCK + t];
    __syncthreads();
    int beg = blockIdx.x * CCHUNK, end = beg + CCHUNK;
    for (int e = beg + t; e < end; e += 256) {
        int g = cand[2 * e], u = cand[2 * e + 1];
        int k = g >> 9;
        int pos = atomicAdd(&loc[k], 1);
        int w0 = g | (u << 17);
        int w1 = (int)(((unsigned)u >> 15) | ((unsigned)e << 2));
        sc[pos] = make_int2(w0, w1);
    }
}

// ======================= shared pipeline kernels =======================

// ---- phaseD: per-bucket counting sort; pairs staged in LDS on pass 1 ----
// Bucket size ~16327 +/- 128; DCAP=17920 is +12 sigma. i >= DCAP falls back
// to the global read (correct for any distribution).
__global__ __launch_bounds__(1024) void phaseD(const int* __restrict__ bbase,
                                               const int* __restrict__ pairs,
                                               int* __restrict__ csr_src,
                                               int* __restrict__ node_off) {
    __shared__ int cnt[512], scn[512], base[512];
    __shared__ int lpairs[DCAP];   // 70 KB; total ~78 KB (1 block/CU, grid=196)
    int t = threadIdx.x, k = blockIdx.x;
    if (t < 512) cnt[t] = 0;
    __syncthreads();
    int beg = bbase[k], end = bbase[k + 1];
    int len = end - beg;
    for (int i = t; i < len; i += 1024) {
        int p = pairs[beg + i];
        if (i < DCAP) lpairs[i] = p;
        atomicAdd(&cnt[p & 511], 1);
    }
    __syncthreads();
    if (t < 512) scn[t] = cnt[t];
    __syncthreads();
    for (int off = 1; off < 512; off <<= 1) {
        int v = 0;
        if (t < 512 && t >= off) v = scn[t - off];
        __syncthreads();
        if (t < 512) scn[t] += v;
        __syncthreads();
    }
    if (t < 512) {
        int bse = beg + scn[t] - cnt[t];
        base[t] = bse;
        node_off[(k << 9) + t] = bse;        // bucket 195 bins >= 160 empty,
                                             // so node_off[100000] == E_CNT.
    }
    __syncthreads();
    for (int i = t; i < len; i += 1024) {
        int p = (i < DCAP) ? lpairs[i] : pairs[beg + i];
        int pos = atomicAdd(&base[p & 511], 1);
        csr_src[pos] = p >> 9;
    }
}

// ---- conv1: CSR register aggregation, 8 lanes/node, 4-deep load pipeline ----
// avg degree 32 -> the whole node's gathers are in flight in one iteration.
__global__ __launch_bounds__(256) void conv1_csr(const int* __restrict__ node_off,
                                                 const int* __restrict__ csr_src,
                                                 const float* __restrict__ x,
                                                 const float* __restrict__ w_rel,
                                                 const float* __restrict__ w_root,
                                                 const float* __restrict__ b,
                                                 float* __restrict__ h1) {
    int t = threadIdx.x;
    int n = blockIdx.x * 32 + (t >> 3);
    int l = t & 7;
    int beg = node_off[n], end = node_off[n + 1];
    float a0 = 0.f, a1 = 0.f, b0 = 0.f, b1v = 0.f;
    float c0 = 0.f, c1 = 0.f, d0 = 0.f, d1 = 0.f;
    int e = beg + l;
    for (; e + 24 < end; e += 32) {
        int s0 = csr_src[e];
        int s1 = csr_src[e + 8];
        int s2 = csr_src[e + 16];
        int s3 = csr_src[e + 24];
        float2 v0 = *(const float2*)(x + 2 * s0);   // 4 independent loads in flight
        float2 v1 = *(const float2*)(x + 2 * s1);
        float2 v2 = *(const float2*)(x + 2 * s2);
        float2 v3 = *(const float2*)(x + 2 * s3);
        a0 += v0.x; a1 += v0.y;
        b0 += v1.x; b1v += v1.y;
        c0 += v2.x; c1 += v2.y;
        d0 += v3.x; d1 += v3.y;
    }
    for (; e < end; e += 8) {
        int s0 = csr_src[e];
        float2 v0 = *(const float2*)(x + 2 * s0);
        a0 += v0.x; a1 += v0.y;
    }
    a0 += b0 + c0 + d0;
    a1 += b1v + c1 + d1;
#pragma unroll
    for (int d = 1; d < 8; d <<= 1) {
        a0 += __shfl_xor(a0, d, 64);
        a1 += __shfl_xor(a1, d, 64);
    }
    float2 xn = *(const float2*)(x + 2 * n);
    float v = a0 * w_rel[l] + a1 * w_rel[8 + l]
            + xn.x * w_root[l] + xn.y * w_root[8 + l] + b[l];
    h1[8 * n + l] = fmaxf(v, 0.f);
}

// ---- conv2_ag16: conv2 + precompA fused, 16 lanes/node, paired-line gather,
//      4-deep load pipeline (each lane-pair keeps 4 independent h1 rows in flight;
//      avg degree 32 means one main-loop iteration covers the whole node) ----
__global__ __launch_bounds__(256) void conv2_ag16(const int* __restrict__ node_off,
                                                  const int* __restrict__ csr_src,
                                                  const float* __restrict__ h1,
                                                  const float* __restrict__ w_rel,
                                                  const float* __restrict__ w_root,
                                                  const float* __restrict__ b,
                                                  const float* __restrict__ wa,
                                                  const float* __restrict__ wprep,
                                                  float* __restrict__ Ag) {
    __shared__ float sh[16][17];   // h2 staging, +1 pad
    int t = threadIdx.x;
    int g = t >> 4, l = t & 15;    // 16 nodes/block, 16 lanes/node
    int pr = l & 1, pe = l >> 1;   // pr: row half, pe: edge slot (0..7)
    int n = blockIdx.x * 16 + g;   // grid 6250*16 == 100000 exactly
    int beg = node_off[n], end = node_off[n + 1];
    float4 a4 = make_float4(0.f, 0.f, 0.f, 0.f);
    float4 b4 = make_float4(0.f, 0.f, 0.f, 0.f);
    float4 c4 = make_float4(0.f, 0.f, 0.f, 0.f);
    float4 d4 = make_float4(0.f, 0.f, 0.f, 0.f);
    int e = beg + pe;
    for (; e + 24 < end; e += 32) {
        int s0 = csr_src[e];
        int s1 = csr_src[e + 8];
        int s2 = csr_src[e + 16];
        int s3 = csr_src[e + 24];
        float4 v0 = *(const float4*)(h1 + 8 * s0 + 4 * pr);
        float4 v1 = *(const float4*)(h1 + 8 * s1 + 4 * pr);
        float4 v2 = *(const float4*)(h1 + 8 * s2 + 4 * pr);
        float4 v3 = *(const float4*)(h1 + 8 * s3 + 4 * pr);
        a4.x += v0.x; a4.y += v0.y; a4.z += v0.z; a4.w += v0.w;
        b4.x += v1.x; b4.y += v1.y; b4.z += v1.z; b4.w += v1.w;
        c4.x += v2.x; c4.y += v2.y; c4.z += v2.z; c4.w += v2.w;
        d4.x += v3.x; d4.y += v3.y; d4.z += v3.z; d4.w += v3.w;
    }
    for (; e < end; e += 8) {
        int s0 = csr_src[e];
        float4 v0 = *(const float4*)(h1 + 8 * s0 + 4 * pr);
        a4.x += v0.x; a4.y += v0.y; a4.z += v0.z; a4.w += v0.w;
    }
    a4.x += b4.x + c4.x + d4.x;
    a4.y += b4.y + c4.y + d4.y;
    a4.z += b4.z + c4.z + d4.z;
    a4.w += b4.w + c4.w + d4.w;
    // butterfly over edge slots (xor 2,4,8 stays within the 16-lane group):
#pragma unroll
    for (int d = 2; d < 16; d <<= 1) {
        a4.x += __shfl_xor(a4.x, d);
        a4.y += __shfl_xor(a4.y, d);
        a4.z += __shfl_xor(a4.z, d);
        a4.w += __shfl_xor(a4.w, d);
    }
    // exchange halves: every lane assembles the full 8-dim aggregate
    float o0 = __shfl_xor(a4.x, 1), o1 = __shfl_xor(a4.y, 1);
    float o2 = __shfl_xor(a4.z, 1), o3 = __shfl_xor(a4.w, 1);
    float agg[8];
    if (pr == 0) {
        agg[0] = a4.x; agg[1] = a4.y; agg[2] = a4.z; agg[3] = a4.w;
        agg[4] = o0;   agg[5] = o1;   agg[6] = o2;   agg[7] = o3;
    } else {
        agg[0] = o0;   agg[1] = o1;   agg[2] = o2;   agg[3] = o3;
        agg[4] = a4.x; agg[5] = a4.y; agg[6] = a4.z; agg[7] = a4.w;
    }
    // root term: all 16 lanes read node n's row (1-2 lines, broadcast)
    const float4* hp = (const float4*)(h1 + 8 * n);
    float4 t0 = hp[0], t1 = hp[1];
    float hn[8] = {t0.x, t0.y, t0.z, t0.w, t1.x, t1.y, t1.z, t1.w};
    // h2 dim c = l (one per lane)
    {
        int c = l;
        float v = b[c];
#pragma unroll
        for (int j = 0; j < 8; j++)
            v += agg[j] * w_rel[j * 16 + c] + hn[j] * w_root[j * 16 + c];
        sh[g][c] = fmaxf(v, 0.f);
    }
    __syncthreads();
    // A-row: lane l computes j in [4l, 4l+4); 16 lanes x 16B = 256B coalesced
    float4 a = *(const float4*)(wprep + 1152 + 4 * l);
#pragma unroll
    for (int i = 0; i < 16; i++) {
        float hi = sh[g][i];
        float4 w = *(const float4*)(wa + i * 64 + 4 * l);
        a.x += hi * w.x; a.y += hi * w.y; a.z += hi * w.z; a.w += hi * w.w;
    }
    *(float4*)(Ag + 64 * n + 4 * l) = a;
}

// ---- fallback: conv2 writing h2 + separate precompA (Ag overlays csr there) ----
__global__ __launch_bounds__(256) void conv2_csr(const int* __restrict__ node_off,
                                                 const int* __restrict__ csr_src,
                                                 const float* __restrict__ h1,
                                                 const float* __restrict__ w_rel,
                                                 const float* __restrict__ w_root,
                                                 const float* __restrict__ b,
                                                 float* __restrict__ h2) {
    int t = threadIdx.x;
    int n = blockIdx.x * 32 + (t >> 3);
    int l = t & 7;
    int beg = node_off[n], end = node_off[n + 1];
    float acc[8] = {0.f, 0.f, 0.f, 0.f, 0.f, 0.f, 0.f, 0.f};
    for (int e = beg + l; e < end; e += 8) {
        int s = csr_src[e];
        const float4* hp = (const float4*)(h1 + 8 * s);
        float4 v0 = hp[0], v1 = hp[1];
        acc[0] += v0.x; acc[1] += v0.y; acc[2] += v0.z; acc[3] += v0.w;
        acc[4] += v1.x; acc[5] += v1.y; acc[6] += v1.z; acc[7] += v1.w;
    }
#pragma unroll
    for (int d = 1; d < 8; d <<= 1)
#pragma unroll
        for (int j = 0; j < 8; j++)
            acc[j] += __shfl_xor(acc[j], d, 64);
    const float4* hp = (const float4*)(h1 + 8 * n);
    float4 t0 = hp[0], t1 = hp[1];
    float hn[8] = {t0.x, t0.y, t0.z, t0.w, t1.x, t1.y, t1.z, t1.w};
#pragma unroll
    for (int cc = 0; cc < 2; cc++) {
        int c = l + 8 * cc;
        float v = b[c];
#pragma unroll
        for (int j = 0; j < 8; j++)
            v += acc[j] * w_rel[j * 16 + c] + hn[j] * w_root[j * 16 + c];
        h2[16 * n + c] = fmaxf(v, 0.f);
    }
}

__global__ __launch_bounds__(256) void precompA(const float* __restrict__ h2,
                                                const float* __restrict__ wa,
                                                const float* __restrict__ wprep,
                                                float* __restrict__ Ag) {
    int g = blockIdx.x * 256 + threadIdx.x;
    if (g >= NG_) return;
    float h[16];
    const float4* hp = (const float4*)(h2 + 16 * g);
#pragma unroll
    for (int q = 0; q < 4; q++) {
        float4 v = hp[q];
        h[4*q] = v.x; h[4*q+1] = v.y; h[4*q+2] = v.z; h[4*q+3] = v.w;
    }
    float4* op = (float4*)(Ag + 64 * g);
#pragma unroll
    for (int q = 0; q < 16; q++) {
        float4 v;
        v.x = wprep[1152 + 4*q + 0];
        v.y = wprep[1152 + 4*q + 1];
        v.z = wprep[1152 + 4*q + 2];
        v.w = wprep[1152 + 4*q + 3];
#pragma unroll
        for (int i = 0; i < 16; i++) {
            float hi = h[i];
            v.x += hi * wa[i*64 + 4*q + 0];
            v.y += hi * wa[i*64 + 4*q + 1];
            v.z += hi * wa[i*64 + 4*q + 2];
            v.w += hi * wa[i*64 + 4*q + 3];
        }
        op[q] = v;
    }
}

// ---- final MLP v7: 8 lanes per candidate, coalesced 256B row reads ----
__global__ __launch_bounds__(256) void final_mlp7(const int2* __restrict__ sc,
                                                  const float* __restrict__ Ag,
                                                  const float* __restrict__ x,
                                                  const float* __restrict__ wprep,
                                                  const float* __restrict__ wb,
                                                  const float* __restrict__ bb,
                                                  float* __restrict__ out) {
    // m204 bijective chunked swizzle (keep sorted candidates XCD-local)
    int nwg = gridDim.x;
    int xcd = blockIdx.x & 7, pos = blockIdx.x >> 3;
    int q = nwg >> 3, r = nwg & 7;
    int wg = (xcd < r ? xcd * (q + 1) : r * (q + 1) + (xcd - r) * q) + pos;

    int t = threadIdx.x;
    int l = t & 7;
    int grp = t >> 3;
    float4 c0lo = *(const float4*)(wprep + 1024 + 4 * l);
    float4 c0hi = *(const float4*)(wprep + 1024 + 32 + 4 * l);
    float4 c1lo = *(const float4*)(wprep + 1088 + 4 * l);
    float4 c1hi = *(const float4*)(wprep + 1088 + 32 + 4 * l);
    float4 wblo = *(const float4*)(wb + 4 * l);
    float4 wbhi = *(const float4*)(wb + 32 + 4 * l);
    float bb0 = bb[0];

    int base = wg * 256;
#pragma unroll 2
    for (int it = 0; it < 8; ++it) {
        int c = base + it * 32 + grp;
        if (c < C_CNT) {
            int2 w = sc[c];
            unsigned w0 = (unsigned)w.x, w1 = (unsigned)w.y;
            int g   = (int)(w0 & 0x1FFFFu);
            int u   = (int)((w0 >> 17) | ((w1 & 3u) << 15));
            int idx = (int)(w1 >> 2);
            float2 xv = *(const float2*)(x + 2 * (NG_ + u));
            const float* rp = Ag + 64 * g;
            float4 alo = *(const float4*)(rp + 4 * l);
            float4 ahi = *(const float4*)(rp + 32 + 4 * l);
            float acc;
            {
                float v0 = alo.x + xv.x * c0lo.x + xv.y * c1lo.x;
                float v1 = alo.y + xv.x * c0lo.y + xv.y * c1lo.y;
                float v2 = alo.z + xv.x * c0lo.z + xv.y * c1lo.z;
                float v3 = alo.w + xv.x * c0lo.w + xv.y * c1lo.w;
                acc  = fmaxf(v0, 0.f) * wblo.x;
                acc += fmaxf(v1, 0.f) * wblo.y;
                acc += fmaxf(v2, 0.f) * wblo.z;
                acc += fmaxf(v3, 0.f) * wblo.w;
            }
            {
                float v0 = ahi.x + xv.x * c0hi.x + xv.y * c1hi.x;
                float v1 = ahi.y + xv.x * c0hi.y + xv.y * c1hi.y;
                float v2 = ahi.z + xv.x * c0hi.z + xv.y * c1hi.z;
                float v3 = ahi.w + xv.x * c0hi.w + xv.y * c1hi.w;
                acc += fmaxf(v0, 0.f) * wbhi.x;
                acc += fmaxf(v1, 0.f) * wbhi.y;
                acc += fmaxf(v2, 0.f) * wbhi.z;
                acc += fmaxf(v3, 0.f) * wbhi.w;
            }
            acc += __shfl_xor(acc, 1);
            acc += __shfl_xor(acc, 2);
            acc += __shfl_xor(acc, 4);
            if (l == 0) out[idx] = acc + bb0;
        }
    }
}

// ======================= launch =======================

extern "C" void kernel_launch(void* const* d_in, const int* in_sizes, int n_in,
                              void* d_out, int out_size, void* d_ws, size_t ws_size,
                              hipStream_t stream) {
    const float* x      = (const float*)d_in[0];
    const int*   cand   = (const int*)d_in[2];
    const int*   edges  = (const int*)d_in[3];   // [2, E]: src then dst
    const float* w1_rel = (const float*)d_in[4];
    const float* w1_root= (const float*)d_in[5];
    const float* b1     = (const float*)d_in[6];
    const float* w2_rel = (const float*)d_in[7];
    const float* w2_root= (const float*)d_in[8];
    const float* b2     = (const float*)d_in[9];
    const float* wu     = (const float*)d_in[10];
    const float* bu     = (const float*)d_in[11];
    const float* wa     = (const float*)d_in[12];
    const float* ba     = (const float*)d_in[13];
    const float* wb     = (const float*)d_in[14];
    const float* bb     = (const float*)d_in[15];
    float* out = (float*)d_out;

    const int* src = edges;
    const int* dst = edges + E_CNT;

    // Base layout (int units), 9,002,944 ints = 36.0 MB:
    //   cnt_mat  [0         .. 50,176)
    //   off_mat  [50,176    .. 100,352)
    //   colsum   [100,352   .. 100,548)
    //   bbase    [100,608   .. 100,805)
    //   node_off [100,864   .. 201,728)
    //   wprep    [201,728   .. 202,944)
    //   pairs    [202,944   .. 3,402,944)
    //   csr_src  [3,402,944 .. 6,602,944)
    //   h1 (f)   [6,602,944 .. 7,402,944)
    //   h2 (f)   [7,402,944 .. 9,002,944)   (fallback only)
    // EXT extras (needs 17,503,808 ints = 70.0 MB; harness fill showed 256 MiB):
    //   cnt2   [9,002,944 .. 9,053,120)
    //   off2   [9,053,120 .. 9,103,296)
    //   csum2  [9,103,296 .. 9,103,492)  pad-> 9,103,552
    //   bbase2 [9,103,552 .. 9,103,749)  pad-> 9,103,808
    //   sc     [9,103,808 .. 11,103,808)  (1M int2, 8B-aligned)
    //   Ag     [11,103,808 .. 17,503,808) (6.4M floats, FRESH: conv2_ag16 still
    //           reads csr_src so the old csr overlay is illegal in ext path)
    // FALLBACK (round-5 proven): cnt2/off2/csum2/bbase2 overlay cnt_mat/off_mat/
    //   colsum/bbase; Ag overlays pairs+csr; sc overlays h1+h2; sort after precompA.
    int* ws_i = (int*)d_ws;
    int*   cnt_mat  = ws_i;
    int*   off_mat  = ws_i + 50176;
    int*   colsum   = ws_i + 100352;
    int*   bbase    = ws_i + 100608;
    int*   node_off = ws_i + 100864;
    float* wprep    = (float*)(ws_i + 201728);
    int*   pairs    = ws_i + 202944;
    int*   csr_src  = ws_i + 3402944;
    float* h1       = (float*)(ws_i + 6602944);
    float* h2       = (float*)(ws_i + 7402944);

    bool ext = ws_size >= (size_t)17503808 * sizeof(int);

    dim3 blk256(256);
    dim3 blk1024(1024);

    if (ext) {
        int*   cnt2   = ws_i + 9002944;
        int*   off2   = ws_i + 9053120;
        int*   csum2  = ws_i + 9103296;
        int*   bbase2 = ws_i + 9103552;
        int2*  sc     = (int2*)(ws_i + 9103808);
        float* Ag     = (float*)(ws_i + 11103808);

        phaseA_f <<<NBLK, blk1024, 0, stream>>>(dst, cand, cnt_mat, cnt2);
        phaseB1_f<<<2 * NBUCK, blk256, 0, stream>>>(cnt_mat, cnt2, off_mat, off2,
                                                    colsum, csum2);
        phaseB2_f<<<1, blk256, 0, stream>>>(colsum, csum2, bbase, bbase2,
                                            wu, bu, wa, ba, wprep);
        phaseC_f <<<NBLK, blk1024, 0, stream>>>(src, dst, off_mat, bbase,
                                                cand, off2, bbase2, pairs, sc);
        phaseD <<<NBUCK, blk1024, 0, stream>>>(bbase, pairs, csr_src, node_off);
        conv1_csr<<<3125, blk256, 0, stream>>>(node_off, csr_src, x, w1_rel, w1_root, b1, h1);
        conv2_ag16<<<6250, blk256, 0, stream>>>(node_off, csr_src, h1, w2_rel, w2_root, b2,
                                                wa, wprep, Ag);
        final_mlp7<<<(C_CNT + 255) / 256, blk256, 0, stream>>>(sc, Ag, x, wprep, wb, bb, out);
    } else {
        int*   cnt2   = ws_i;                     // overlay cnt_mat
        int*   off2   = ws_i + 50176;             // overlay off_mat
        int*   csum2  = ws_i + 100352;            // overlay colsum
        int*   bbase2 = ws_i + 100608;            // overlay bbase
        int2*  sc     = (int2*)(ws_i + 6602944);  // overlay h1+h2
        float* Ag     = (float*)(ws_i + 202944);  // overlay pairs+csr_src

        prep_kernel<<<1, 64, 0, stream>>>(wu, bu, wa, ba, wprep);
        phaseA <<<NBLK, blk256, 0, stream>>>(dst, cnt_mat);
        phaseB1<<<NBUCK, blk256, 0, stream>>>(cnt_mat, off_mat, colsum);
        phaseB2<<<1, blk256, 0, stream>>>(colsum, bbase);
        phaseC <<<NBLK, blk256, 0, stream>>>(src, dst, off_mat, bbase, pairs);
        phaseD <<<NBUCK, blk1024, 0, stream>>>(bbase, pairs, csr_src, node_off);
        conv1_csr<<<3125, blk256, 0, stream>>>(node_off, csr_src, x, w1_rel, w1_root, b1, h1);
        conv2_csr<<<3125, blk256, 0, stream>>>(node_off, csr_src, h1, w2_rel, w2_root, b2, h2);
        precompA<<<(NG_ + 255) / 256, blk256, 0, stream>>>(h2, wa, wprep, Ag);
        candA <<<CBLK, blk256, 0, stream>>>(cand, cnt2);
        candB1<<<NBUCK, blk256, 0, stream>>>(cnt2, off2, csum2);
        candB2<<<1, blk256, 0, stream>>>(csum2, bbase2);
        candC <<<CBLK, blk256, 0, stream>>>(cand, off2, bbase2, sc);
        final_mlp7<<<(C_CNT + 255) / 256, blk256, 0, stream>>>(sc, Ag, x, wprep, wb, bb, out);
    }
}